// Round 1
// baseline (6696.555 us; speedup 1.0000x reference)
//
#include <hip/hip_runtime.h>
#include <hip/hip_bf16.h>
#include <math.h>

#define BT 4096      // B*T tokens
#define HD 1024      // hidden
#define NHEAD 16
#define DH 64
#define ED 512       // expert dim
#define NEXP 10
#define TOPKE 3
#define NLAYER 4
#define NVOCAB 32000
#define NSLOT (BT * TOPKE)   // 12288

__device__ __forceinline__ float gelu_f(float x) {
  return 0.5f * x * (1.0f + erff(x * 0.70710678118654752440f));
}

// ---------------- embedding: h = W_emb[x] + W_pos[pos] ----------------
__global__ __launch_bounds__(256) void k_embed(const int* __restrict__ x,
                                               const float* __restrict__ Wemb,
                                               const float* __restrict__ Wpos,
                                               float* __restrict__ h) {
  const int t = blockIdx.x;           // 0..4095
  const int pos = t & 1023;
  const int tok = x[t];
  const float4* we = (const float4*)(Wemb + (size_t)tok * HD);
  const float4* wp = (const float4*)(Wpos + (size_t)pos * HD);
  float4* ho = (float4*)(h + (size_t)t * HD);
  const int i = threadIdx.x;          // 256 threads cover 256 float4
  float4 a = we[i], b = wp[i];
  ho[i] = make_float4(a.x + b.x, a.y + b.y, a.z + b.z, a.w + b.w);
}

// ---------------- layernorm over rows of HD ----------------
__global__ __launch_bounds__(256) void k_ln(const float* __restrict__ in,
                                            const float* __restrict__ g,
                                            const float* __restrict__ b,
                                            float* __restrict__ out) {
  const int row = blockIdx.x;
  const int tid = threadIdx.x;
  const float* xr = in + (size_t)row * HD;
  float s = 0.f, ss = 0.f;
  for (int i = tid; i < HD; i += 256) { float v = xr[i]; s += v; ss += v * v; }
#pragma unroll
  for (int o = 32; o > 0; o >>= 1) { s += __shfl_down(s, o); ss += __shfl_down(ss, o); }
  __shared__ float rs[4], rss[4];
  if ((tid & 63) == 0) { rs[tid >> 6] = s; rss[tid >> 6] = ss; }
  __syncthreads();
  const float S = rs[0] + rs[1] + rs[2] + rs[3];
  const float SS = rss[0] + rss[1] + rss[2] + rss[3];
  const float mean = S * (1.0f / HD);
  const float var = SS * (1.0f / HD) - mean * mean;
  const float inv = rsqrtf(var + 1e-5f);
  float* orow = out + (size_t)row * HD;
  for (int i = tid; i < HD; i += 256) {
    float v = xr[i];
    orow[i] = (v - mean) * inv * g[i] + b[i];
  }
}

// final LN over the 4 last-token rows only
__global__ __launch_bounds__(256) void k_lnf(const float* __restrict__ h,
                                             const float* __restrict__ g,
                                             const float* __restrict__ b,
                                             float* __restrict__ hf) {
  const int row = blockIdx.x * 1024 + 1023;
  const int tid = threadIdx.x;
  const float* xr = h + (size_t)row * HD;
  float s = 0.f, ss = 0.f;
  for (int i = tid; i < HD; i += 256) { float v = xr[i]; s += v; ss += v * v; }
#pragma unroll
  for (int o = 32; o > 0; o >>= 1) { s += __shfl_down(s, o); ss += __shfl_down(ss, o); }
  __shared__ float rs[4], rss[4];
  if ((tid & 63) == 0) { rs[tid >> 6] = s; rss[tid >> 6] = ss; }
  __syncthreads();
  const float S = rs[0] + rs[1] + rs[2] + rs[3];
  const float SS = rss[0] + rss[1] + rss[2] + rss[3];
  const float mean = S * (1.0f / HD);
  const float var = SS * (1.0f / HD) - mean * mean;
  const float inv = rsqrtf(var + 1e-5f);
  float* orow = hf + (size_t)blockIdx.x * HD;
  for (int i = tid; i < HD; i += 256) {
    float v = xr[i];
    orow[i] = (v - mean) * inv * g[i] + b[i];
  }
}

// ---------------- dense fp32 GEMM: C = A[M,K] @ B[K,N]  (64x64 tiles) ---------
// EPI: 0 = none, 1 = gelu, 2 = add residual R
template <int EPI>
__global__ __launch_bounds__(256) void k_gemm(const float* __restrict__ A,
                                              const float* __restrict__ B,
                                              const float* __restrict__ R,
                                              float* __restrict__ C,
                                              int M, int N, int K) {
  __shared__ float As[64][17];
  __shared__ float Bs[16][64];
  const int tid = threadIdx.x;
  const int tx = tid & 15, ty = tid >> 4;
  const int m0 = blockIdx.y << 6, n0 = blockIdx.x << 6;
  const int ar = tid >> 2, ak = (tid & 3) << 2;
  const int bk = tid >> 4, bc = (tid & 15) << 2;
  float acc[4][4] = {};
  for (int k0 = 0; k0 < K; k0 += 16) {
    float4 av = *(const float4*)(A + (size_t)(m0 + ar) * K + k0 + ak);
    As[ar][ak] = av.x; As[ar][ak + 1] = av.y; As[ar][ak + 2] = av.z; As[ar][ak + 3] = av.w;
    float4 bv = *(const float4*)(B + (size_t)(k0 + bk) * N + n0 + bc);
    *(float4*)&Bs[bk][bc] = bv;
    __syncthreads();
#pragma unroll
    for (int kk = 0; kk < 16; ++kk) {
      float a[4], bb[4];
#pragma unroll
      for (int i = 0; i < 4; ++i) a[i] = As[ty * 4 + i][kk];
#pragma unroll
      for (int j = 0; j < 4; ++j) bb[j] = Bs[kk][tx * 4 + j];
#pragma unroll
      for (int i = 0; i < 4; ++i)
#pragma unroll
        for (int j = 0; j < 4; ++j) acc[i][j] = fmaf(a[i], bb[j], acc[i][j]);
    }
    __syncthreads();
  }
#pragma unroll
  for (int i = 0; i < 4; ++i) {
    const int row = m0 + ty * 4 + i;
    float vv[4];
#pragma unroll
    for (int j = 0; j < 4; ++j) {
      float t = acc[i][j];
      if (EPI == 1) t = gelu_f(t);
      else if (EPI == 2) t += R[(size_t)row * N + n0 + tx * 4 + j];
      vv[j] = t;
    }
    *(float4*)(C + (size_t)row * N + n0 + tx * 4) = make_float4(vv[0], vv[1], vv[2], vv[3]);
  }
}

// ---------------- grouped MoE GEMM over expert-sorted slots ----------------
// EPI: 1 = gelu (up proj), 3 = scale by gate (down proj)
template <int EPI>
__global__ __launch_bounds__(256) void k_gemm_moe(const float* __restrict__ A,
                                                  const float* __restrict__ Bbase,
                                                  float* __restrict__ C,
                                                  const int* __restrict__ tile_e,
                                                  const int* __restrict__ tile_r0,
                                                  const int* __restrict__ ntiles,
                                                  const int* __restrict__ counts,
                                                  const int* __restrict__ offs,
                                                  const int* __restrict__ row_slot,
                                                  const float* __restrict__ gate_slot,
                                                  int N, int K, int gather) {
  const int tile = blockIdx.y;
  if (tile >= *ntiles) return;
  const int e = tile_e[tile], r0 = tile_r0[tile];
  const int cnt = counts[e], off = offs[e];
  const float* B = Bbase + (size_t)e * K * N;
  __shared__ float As[64][17];
  __shared__ float Bs[16][64];
  const int tid = threadIdx.x;
  const int tx = tid & 15, ty = tid >> 4;
  const int n0 = blockIdx.x << 6;
  const int ar = tid >> 2, ak = (tid & 3) << 2;
  const int bk = tid >> 4, bc = (tid & 15) << 2;
  const bool aok = (r0 + ar) < cnt;
  int arow = 0;
  if (aok) {
    int slot = off + r0 + ar;
    arow = gather ? row_slot[slot] : slot;
  }
  float acc[4][4] = {};
  for (int k0 = 0; k0 < K; k0 += 16) {
    if (aok) {
      float4 av = *(const float4*)(A + (size_t)arow * K + k0 + ak);
      As[ar][ak] = av.x; As[ar][ak + 1] = av.y; As[ar][ak + 2] = av.z; As[ar][ak + 3] = av.w;
    } else {
      As[ar][ak] = 0.f; As[ar][ak + 1] = 0.f; As[ar][ak + 2] = 0.f; As[ar][ak + 3] = 0.f;
    }
    float4 bv = *(const float4*)(B + (size_t)(k0 + bk) * N + n0 + bc);
    *(float4*)&Bs[bk][bc] = bv;
    __syncthreads();
#pragma unroll
    for (int kk = 0; kk < 16; ++kk) {
      float a[4], bb[4];
#pragma unroll
      for (int i = 0; i < 4; ++i) a[i] = As[ty * 4 + i][kk];
#pragma unroll
      for (int j = 0; j < 4; ++j) bb[j] = Bs[kk][tx * 4 + j];
#pragma unroll
      for (int i = 0; i < 4; ++i)
#pragma unroll
        for (int j = 0; j < 4; ++j) acc[i][j] = fmaf(a[i], bb[j], acc[i][j]);
    }
    __syncthreads();
  }
#pragma unroll
  for (int i = 0; i < 4; ++i) {
    const int rl = ty * 4 + i;
    if (r0 + rl < cnt) {
      const int slot = off + r0 + rl;
      const float sc = (EPI == 3) ? gate_slot[slot] : 1.0f;
      float vv[4];
#pragma unroll
      for (int j = 0; j < 4; ++j) {
        float t = acc[i][j];
        if (EPI == 1) t = gelu_f(t);
        else t *= sc;
        vv[j] = t;
      }
      *(float4*)(C + (size_t)slot * N + n0 + tx * 4) = make_float4(vv[0], vv[1], vv[2], vv[3]);
    }
  }
}

// ---------------- flash attention, fp32, 64x64 tiles ----------------
// qkv layout per token row (3072): [q(16 heads x 64) | k | v]
__global__ __launch_bounds__(256) void k_attn(const float* __restrict__ qkv,
                                              float* __restrict__ y) {
  const int bh = blockIdx.x;      // 0..63
  const int qt = blockIdx.y;      // 0..15
  const int b = bh >> 4, hh = bh & 15;
  const int tid = threadIdx.x;
  const int r = tid & 63, g = tid >> 6;   // wave g owns 16 columns / 16 dims
  __shared__ float Qs[64][65];
  __shared__ float Ks[64][65];
  __shared__ float Vs[64][65];
  __shared__ float Ps[64][65];
  __shared__ float wred[4][64];
  __shared__ float rowm[64], rowl[64];
  const size_t base = (size_t)b * 1024 * 3072;
  for (int i = tid; i < 64 * 16; i += 256) {
    int rr = i >> 4, dq = (i & 15) * 4;
    float4 v = *(const float4*)(qkv + base + (size_t)(qt * 64 + rr) * 3072 + hh * 64 + dq);
    Qs[rr][dq] = v.x; Qs[rr][dq + 1] = v.y; Qs[rr][dq + 2] = v.z; Qs[rr][dq + 3] = v.w;
  }
  if (g == 0) { rowm[r] = -INFINITY; rowl[r] = 0.0f; }
  float yacc[16];
#pragma unroll
  for (int i = 0; i < 16; ++i) yacc[i] = 0.0f;
  const int qg = qt * 64 + r;
  for (int kt = 0; kt <= qt; ++kt) {
    __syncthreads();   // prior-iter readers of Ks/Vs/Ps done; Q/rowm visible
    for (int i = tid; i < 64 * 16; i += 256) {
      int rr = i >> 4, dq = (i & 15) * 4;
      float4 kv = *(const float4*)(qkv + base + (size_t)(kt * 64 + rr) * 3072 + 1024 + hh * 64 + dq);
      Ks[rr][dq] = kv.x; Ks[rr][dq + 1] = kv.y; Ks[rr][dq + 2] = kv.z; Ks[rr][dq + 3] = kv.w;
      float4 vv = *(const float4*)(qkv + base + (size_t)(kt * 64 + rr) * 3072 + 2048 + hh * 64 + dq);
      Vs[rr][dq] = vv.x; Vs[rr][dq + 1] = vv.y; Vs[rr][dq + 2] = vv.z; Vs[rr][dq + 3] = vv.w;
    }
    __syncthreads();
    float s[16];
    float tmax = -INFINITY;
#pragma unroll 4
    for (int jj = 0; jj < 16; ++jj) {
      const int j = g * 16 + jj;
      float acc = 0.0f;
#pragma unroll
      for (int d = 0; d < 64; ++d) acc += Qs[r][d] * Ks[j][d];
      acc *= 0.125f;
      if (kt * 64 + j > qg) acc = -INFINITY;
      s[jj] = acc;
      tmax = fmaxf(tmax, acc);
    }
    wred[g][r] = tmax;
    __syncthreads();
    const float mt = fmaxf(fmaxf(wred[0][r], wred[1][r]), fmaxf(wred[2][r], wred[3][r]));
    const float mold = rowm[r];
    const float mnew = fmaxf(mold, mt);
    const float factor = __expf(mold - mnew);   // mold=-inf -> 0
    __syncthreads();   // everyone done reading wred/rowm
    float tsum = 0.0f;
#pragma unroll
    for (int jj = 0; jj < 16; ++jj) {
      float p = __expf(s[jj] - mnew);           // masked: exp(-inf)=0
      Ps[r][g * 16 + jj] = p;
      tsum += p;
    }
    wred[g][r] = tsum;
#pragma unroll
    for (int dd = 0; dd < 16; ++dd) yacc[dd] *= factor;
    __syncthreads();
    if (g == 0) {
      rowl[r] = rowl[r] * factor + wred[0][r] + wred[1][r] + wred[2][r] + wred[3][r];
      rowm[r] = mnew;
    }
#pragma unroll 8
    for (int j = 0; j < 64; ++j) {
      const float p = Ps[r][j];
#pragma unroll
      for (int dd = 0; dd < 16; ++dd) yacc[dd] += p * Vs[j][g * 16 + dd];
    }
  }
  __syncthreads();
  const float inv = 1.0f / rowl[r];
  float* yo = y + (size_t)(b * 1024 + qt * 64 + r) * HD + hh * 64 + g * 16;
#pragma unroll
  for (int q4 = 0; q4 < 4; ++q4) {
    *(float4*)(yo + q4 * 4) = make_float4(yacc[q4 * 4] * inv, yacc[q4 * 4 + 1] * inv,
                                          yacc[q4 * 4 + 2] * inv, yacc[q4 * 4 + 3] * inv);
  }
}

// ---------------- router: softmax(x@Wr), top-3, counts ----------------
__global__ __launch_bounds__(64) void k_router(const float* __restrict__ xln,
                                               const float* __restrict__ Wr,
                                               float* __restrict__ gates,
                                               int* __restrict__ eidx,
                                               int* __restrict__ counts) {
  const int t = blockIdx.x;
  const int lane = threadIdx.x;
  const float* xr = xln + (size_t)t * HD;
  float partial[NEXP];
#pragma unroll
  for (int e = 0; e < NEXP; ++e) partial[e] = 0.f;
  for (int k = lane; k < HD; k += 64) {
    const float xv = xr[k];
    const float* wrow = Wr + (size_t)k * NEXP;
#pragma unroll
    for (int e = 0; e < NEXP; ++e) partial[e] += xv * wrow[e];
  }
  __shared__ float lg[NEXP];
#pragma unroll
  for (int e = 0; e < NEXP; ++e) {
    float v = partial[e];
#pragma unroll
    for (int o = 32; o > 0; o >>= 1) v += __shfl_down(v, o);
    if (lane == 0) lg[e] = v;
  }
  __syncthreads();
  if (lane == 0) {
    float m = lg[0];
#pragma unroll
    for (int e = 1; e < NEXP; ++e) m = fmaxf(m, lg[e]);
    float p[NEXP], sum = 0.f;
#pragma unroll
    for (int e = 0; e < NEXP; ++e) { p[e] = __expf(lg[e] - m); sum += p[e]; }
    const float isum = 1.0f / sum;
#pragma unroll
    for (int e = 0; e < NEXP; ++e) p[e] *= isum;
    bool used[NEXP] = {};
    for (int k = 0; k < TOPKE; ++k) {
      int best = -1; float bv = -1.f;
      for (int e = 0; e < NEXP; ++e)
        if (!used[e] && p[e] > bv) { bv = p[e]; best = e; }
      used[best] = true;
      eidx[t * TOPKE + k] = best;
      gates[t * TOPKE + k] = bv;
      atomicAdd(&counts[best], 1);
    }
  }
}

__global__ void k_zero(int* p) { if (threadIdx.x < 16) p[threadIdx.x] = 0; }

__global__ void k_prefix(const int* __restrict__ counts, int* __restrict__ offs,
                         int* __restrict__ cursor, int* __restrict__ tile_e,
                         int* __restrict__ tile_r0, int* __restrict__ ntiles) {
  if (threadIdx.x == 0 && blockIdx.x == 0) {
    int off = 0, nt = 0;
    for (int e = 0; e < NEXP; ++e) {
      offs[e] = off; cursor[e] = off;
      const int c = counts[e];
      for (int r0 = 0; r0 < c; r0 += 64) { tile_e[nt] = e; tile_r0[nt] = r0; ++nt; }
      off += c;
    }
    *ntiles = nt;
  }
}

__global__ __launch_bounds__(256) void k_scatter(const int* __restrict__ eidx,
                                                 const float* __restrict__ gates,
                                                 int* __restrict__ cursor,
                                                 int* __restrict__ row_slot,
                                                 float* __restrict__ gate_slot,
                                                 int* __restrict__ slot_of) {
  const int i = blockIdx.x * blockDim.x + threadIdx.x;
  if (i >= NSLOT) return;
  const int e = eidx[i];
  const int pos = atomicAdd(&cursor[e], 1);
  row_slot[pos] = i / TOPKE;
  gate_slot[pos] = gates[i];
  slot_of[i] = pos;
}

// ---------------- combine: h += shared + sum_k routed_down[slot] ----------------
__global__ __launch_bounds__(256) void k_combine(float* __restrict__ h,
                                                 const float* __restrict__ sh,
                                                 const float* __restrict__ rd,
                                                 const int* __restrict__ slot_of) {
  const int t = blockIdx.x;
  const int s0 = slot_of[t * 3 + 0], s1 = slot_of[t * 3 + 1], s2 = slot_of[t * 3 + 2];
  const float4* shp = (const float4*)(sh + (size_t)t * HD);
  const float4* r0 = (const float4*)(rd + (size_t)s0 * HD);
  const float4* r1 = (const float4*)(rd + (size_t)s1 * HD);
  const float4* r2 = (const float4*)(rd + (size_t)s2 * HD);
  float4* hp = (float4*)(h + (size_t)t * HD);
  const int i = threadIdx.x;   // 256 threads = 256 float4 = 1024 floats
  float4 hv = hp[i], a = shp[i], b0 = r0[i], b1 = r1[i], b2 = r2[i];
  hv.x += a.x + b0.x + b1.x + b2.x;
  hv.y += a.y + b0.y + b1.y + b2.y;
  hv.z += a.z + b0.z + b1.z + b2.z;
  hv.w += a.w + b0.w + b1.w + b2.w;
  hp[i] = hv;
}

// ---------------- tied head: logits[b][v] = dot(hf[b], Wemb[v]) ----------------
__global__ __launch_bounds__(256) void k_head(const float* __restrict__ hf,
                                              const float* __restrict__ Wemb,
                                              float* __restrict__ out) {
  __shared__ float hs[4][HD];
  const int tid = threadIdx.x;
  for (int i = tid; i < HD; i += 256) {
    hs[0][i] = hf[i]; hs[1][i] = hf[HD + i];
    hs[2][i] = hf[2 * HD + i]; hs[3][i] = hf[3 * HD + i];
  }
  __syncthreads();
  const int w = tid >> 6, lane = tid & 63;
  for (int i = 0; i < 4; ++i) {
    const int v = blockIdx.x * 16 + w * 4 + i;
    const float4* wr = (const float4*)(Wemb + (size_t)v * HD);
    float a0 = 0.f, a1 = 0.f, a2 = 0.f, a3 = 0.f;
    for (int q = lane; q < HD / 4; q += 64) {
      float4 wv = wr[q];
      const int k = q * 4;
      a0 += wv.x * hs[0][k] + wv.y * hs[0][k + 1] + wv.z * hs[0][k + 2] + wv.w * hs[0][k + 3];
      a1 += wv.x * hs[1][k] + wv.y * hs[1][k + 1] + wv.z * hs[1][k + 2] + wv.w * hs[1][k + 3];
      a2 += wv.x * hs[2][k] + wv.y * hs[2][k + 1] + wv.z * hs[2][k + 2] + wv.w * hs[2][k + 3];
      a3 += wv.x * hs[3][k] + wv.y * hs[3][k + 1] + wv.z * hs[3][k + 2] + wv.w * hs[3][k + 3];
    }
#pragma unroll
    for (int o = 32; o > 0; o >>= 1) {
      a0 += __shfl_down(a0, o); a1 += __shfl_down(a1, o);
      a2 += __shfl_down(a2, o); a3 += __shfl_down(a3, o);
    }
    if (lane == 0) {
      out[v] = a0; out[NVOCAB + v] = a1;
      out[2 * NVOCAB + v] = a2; out[3 * NVOCAB + v] = a3;
    }
  }
}

extern "C" void kernel_launch(void* const* d_in, const int* in_sizes, int n_in,
                              void* d_out, int out_size, void* d_ws, size_t ws_size,
                              hipStream_t stream) {
  (void)in_sizes; (void)n_in; (void)out_size; (void)ws_size;
  const int* x = (const int*)d_in[0];
  const float* W_emb = (const float*)d_in[1];
  const float* W_pos = (const float*)d_in[2];
  const float* ln1_g = (const float*)d_in[3];
  const float* ln1_b = (const float*)d_in[4];
  const float* Wqkv = (const float*)d_in[5];
  const float* Wo = (const float*)d_in[6];
  const float* ln2_g = (const float*)d_in[7];
  const float* ln2_b = (const float*)d_in[8];
  const float* Wr = (const float*)d_in[9];
  const float* Wsu = (const float*)d_in[10];
  const float* Wsd = (const float*)d_in[11];
  const float* Wu = (const float*)d_in[12];
  const float* Wd = (const float*)d_in[13];
  const float* lnf_g = (const float*)d_in[14];
  const float* lnf_b = (const float*)d_in[15];
  float* out = (float*)d_out;

  float* wsf = (float*)d_ws;
  size_t o = 0;
  float* hbuf = wsf + o; o += (size_t)BT * HD;
  float* lno  = wsf + o; o += (size_t)BT * HD;
  float* qkvb = wsf + o; o += (size_t)BT * 3 * HD;   // also routed_down (12288*1024)
  float* yb   = wsf + o; o += (size_t)BT * HD;       // also moe_out (shared expert out)
  float* ab   = wsf + o; o += (size_t)BT * HD;
  float* shm  = wsf + o; o += (size_t)BT * ED;
  float* rup  = wsf + o; o += (size_t)NSLOT * ED;
  float* gates = wsf + o; o += NSLOT;
  float* gate_slot = wsf + o; o += NSLOT;
  float* hf = wsf + o; o += 4 * HD;
  int* eidx = (int*)(wsf + o); o += NSLOT;
  int* row_slot = (int*)(wsf + o); o += NSLOT;
  int* slot_of = (int*)(wsf + o); o += NSLOT;
  int* counts = (int*)(wsf + o); o += 16;
  int* offs = (int*)(wsf + o); o += 16;
  int* cursor = (int*)(wsf + o); o += 16;
  int* tile_e = (int*)(wsf + o); o += 256;
  int* tile_r0 = (int*)(wsf + o); o += 256;
  int* ntiles = (int*)(wsf + o); o += 16;
  float* routed_down = qkvb;
  float* moe_out = yb;

  k_embed<<<BT, 256, 0, stream>>>(x, W_emb, W_pos, hbuf);

  for (int l = 0; l < NLAYER; ++l) {
    k_ln<<<BT, 256, 0, stream>>>(hbuf, ln1_g + (size_t)l * HD, ln1_b + (size_t)l * HD, lno);
    k_gemm<0><<<dim3(48, 64), 256, 0, stream>>>(lno, Wqkv + (size_t)l * HD * 3 * HD, nullptr,
                                                qkvb, BT, 3 * HD, HD);
    k_attn<<<dim3(64, 16), 256, 0, stream>>>(qkvb, yb);
    k_gemm<2><<<dim3(16, 64), 256, 0, stream>>>(yb, Wo + (size_t)l * HD * HD, hbuf,
                                                ab, BT, HD, HD);
    k_ln<<<BT, 256, 0, stream>>>(ab, ln2_g + (size_t)l * HD, ln2_b + (size_t)l * HD, lno);
    k_zero<<<1, 64, 0, stream>>>(counts);
    k_router<<<BT, 64, 0, stream>>>(lno, Wr + (size_t)l * HD * NEXP, gates, eidx, counts);
    k_prefix<<<1, 1, 0, stream>>>(counts, offs, cursor, tile_e, tile_r0, ntiles);
    k_scatter<<<(NSLOT + 255) / 256, 256, 0, stream>>>(eidx, gates, cursor, row_slot,
                                                       gate_slot, slot_of);
    // shared expert
    k_gemm<1><<<dim3(8, 64), 256, 0, stream>>>(lno, Wsu + (size_t)l * HD * ED, nullptr,
                                               shm, BT, ED, HD);
    k_gemm<0><<<dim3(16, 64), 256, 0, stream>>>(shm, Wsd + (size_t)l * ED * HD, nullptr,
                                                moe_out, BT, HD, ED);
    // routed experts (top-3 only; zero-gated experts contribute nothing)
    k_gemm_moe<1><<<dim3(8, 224), 256, 0, stream>>>(lno, Wu + (size_t)l * NEXP * HD * ED, rup,
                                                    tile_e, tile_r0, ntiles, counts, offs,
                                                    row_slot, gate_slot, ED, HD, 1);
    k_gemm_moe<3><<<dim3(16, 224), 256, 0, stream>>>(rup, Wd + (size_t)l * NEXP * ED * HD,
                                                     routed_down, tile_e, tile_r0, ntiles,
                                                     counts, offs, row_slot, gate_slot,
                                                     HD, ED, 0);
    k_combine<<<BT, 256, 0, stream>>>(hbuf, moe_out, routed_down, slot_of);
  }

  k_lnf<<<4, 256, 0, stream>>>(hbuf, lnf_g, lnf_b, hf);
  k_head<<<NVOCAB / 16, 256, 0, stream>>>(hf, W_emb, out);
}

// Round 2
// 3459.644 us; speedup vs baseline: 1.9356x; 1.9356x over previous
//
#include <hip/hip_runtime.h>
#include <hip/hip_bf16.h>
#include <math.h>

#define BT 4096      // B*T tokens
#define HD 1024      // hidden
#define NHEAD 16
#define DH 64
#define ED 512       // expert dim
#define NEXP 10
#define TOPKE 3
#define NLAYER 4
#define NVOCAB 32000
#define NSLOT (BT * TOPKE)   // 12288

typedef __attribute__((ext_vector_type(8))) short bf16x8;
typedef __attribute__((ext_vector_type(4))) float f32x4;

__device__ __forceinline__ float gelu_f(float x) {
  return 0.5f * x * (1.0f + erff(x * 0.70710678118654752440f));
}

// async global->LDS, 16B per lane, 64 lanes = 1KB per call.
// LDS dest = wave-uniform base + lane*16; global src is per-lane.
__device__ __forceinline__ void gll16(const void* g, void* l) {
  __builtin_amdgcn_global_load_lds(
      (const __attribute__((address_space(1))) unsigned int*)g,
      (__attribute__((address_space(3))) unsigned int*)l, 16, 0, 0);
}

// ---------------- embedding: h = W_emb[x] + W_pos[pos] ----------------
__global__ __launch_bounds__(256) void k_embed(const int* __restrict__ x,
                                               const float* __restrict__ Wemb,
                                               const float* __restrict__ Wpos,
                                               float* __restrict__ h) {
  const int t = blockIdx.x;
  const int pos = t & 1023;
  const int tok = x[t];
  const float4* we = (const float4*)(Wemb + (size_t)tok * HD);
  const float4* wp = (const float4*)(Wpos + (size_t)pos * HD);
  float4* ho = (float4*)(h + (size_t)t * HD);
  const int i = threadIdx.x;
  float4 a = we[i], b = wp[i];
  ho[i] = make_float4(a.x + b.x, a.y + b.y, a.z + b.z, a.w + b.w);
}

// ---------------- weight transpose + fp32->bf16: in [z][K][N] -> out [z][N][K]
__global__ __launch_bounds__(256) void k_wtrans(const float* __restrict__ in,
                                                __hip_bfloat16* __restrict__ out,
                                                int K, int N) {
  const int z = blockIdx.z;
  const float* src = in + (size_t)z * K * N;
  __hip_bfloat16* dst = out + (size_t)z * N * K;
  __shared__ float t[32][33];
  const int tx = threadIdx.x, ty = threadIdx.y;    // (32, 8)
  const int k0 = blockIdx.y * 32, n0 = blockIdx.x * 32;
  for (int r = ty; r < 32; r += 8) t[r][tx] = src[(size_t)(k0 + r) * N + n0 + tx];
  __syncthreads();
  for (int r = ty; r < 32; r += 8)
    dst[(size_t)(n0 + r) * K + k0 + tx] = __float2bfloat16(t[tx][r]);
}

// ---------------- layernorm over rows of HD: fp32 + bf16 outputs ----------------
__global__ __launch_bounds__(256) void k_ln(const float* __restrict__ in,
                                            const float* __restrict__ g,
                                            const float* __restrict__ b,
                                            float* __restrict__ outf,
                                            __hip_bfloat16* __restrict__ outb) {
  const int row = blockIdx.x;
  const int tid = threadIdx.x;
  const float* xr = in + (size_t)row * HD;
  float s = 0.f, ss = 0.f;
  for (int i = tid; i < HD; i += 256) { float v = xr[i]; s += v; ss += v * v; }
#pragma unroll
  for (int o = 32; o > 0; o >>= 1) { s += __shfl_down(s, o); ss += __shfl_down(ss, o); }
  __shared__ float rs[4], rss[4];
  if ((tid & 63) == 0) { rs[tid >> 6] = s; rss[tid >> 6] = ss; }
  __syncthreads();
  const float S = rs[0] + rs[1] + rs[2] + rs[3];
  const float SS = rss[0] + rss[1] + rss[2] + rss[3];
  const float mean = S * (1.0f / HD);
  const float var = SS * (1.0f / HD) - mean * mean;
  const float inv = rsqrtf(var + 1e-5f);
  float* orow = outf + (size_t)row * HD;
  __hip_bfloat16* brow = outb + (size_t)row * HD;
  for (int i = tid; i < HD; i += 256) {
    float v = (xr[i] - mean) * inv * g[i] + b[i];
    orow[i] = v;
    brow[i] = __float2bfloat16(v);
  }
}

// final LN over the 4 last-token rows only
__global__ __launch_bounds__(256) void k_lnf(const float* __restrict__ h,
                                             const float* __restrict__ g,
                                             const float* __restrict__ b,
                                             float* __restrict__ hf) {
  const int row = blockIdx.x * 1024 + 1023;
  const int tid = threadIdx.x;
  const float* xr = h + (size_t)row * HD;
  float s = 0.f, ss = 0.f;
  for (int i = tid; i < HD; i += 256) { float v = xr[i]; s += v; ss += v * v; }
#pragma unroll
  for (int o = 32; o > 0; o >>= 1) { s += __shfl_down(s, o); ss += __shfl_down(ss, o); }
  __shared__ float rs[4], rss[4];
  if ((tid & 63) == 0) { rs[tid >> 6] = s; rss[tid >> 6] = ss; }
  __syncthreads();
  const float S = rs[0] + rs[1] + rs[2] + rs[3];
  const float SS = rss[0] + rss[1] + rss[2] + rss[3];
  const float mean = S * (1.0f / HD);
  const float var = SS * (1.0f / HD) - mean * mean;
  const float inv = rsqrtf(var + 1e-5f);
  float* orow = hf + (size_t)blockIdx.x * HD;
  for (int i = tid; i < HD; i += 256) {
    float v = xr[i];
    orow[i] = (v - mean) * inv * g[i] + b[i];
  }
}

// ---------------- bf16 MFMA GEMM: C[M,N] = A[M,K] @ Bt[N,K]^T ----------------
// m97 structure: 128x128 tile, BK=32, 4 waves each owning a 64x64 quadrant
// EPI: 0 none, 1 gelu, 2 +residual R.  OBF: 1 -> bf16 out, 0 -> fp32 out.
template <int EPI, int OBF>
__global__ __launch_bounds__(256) void k_mgemm(const __hip_bfloat16* __restrict__ A,
                                               const __hip_bfloat16* __restrict__ Bt,
                                               const float* __restrict__ R,
                                               float* __restrict__ C,
                                               __hip_bfloat16* __restrict__ Cb,
                                               int M, int N, int K) {
  __shared__ __hip_bfloat16 As[128 * 32];
  __shared__ __hip_bfloat16 Bs[128 * 32];
  const int tid = threadIdx.x;
  const int w = tid >> 6, lane = tid & 63;
  const int wr = w >> 1, wc = w & 1;
  const int m0 = blockIdx.y << 7, n0 = blockIdx.x << 7;
  const int srow = lane >> 2;            // 0..15
  const int scol = (lane & 3) * 8;       // 0,8,16,24
  // LDS fragment offsets (k-invariant)
  const int kq = (lane >> 4) * 8;
  int aidx[4], bidx[4];
#pragma unroll
  for (int m = 0; m < 4; ++m) aidx[m] = (wr * 64 + m * 16 + (lane & 15)) * 32 + kq;
#pragma unroll
  for (int n = 0; n < 4; ++n) bidx[n] = (wc * 64 + n * 16 + (lane & 15)) * 32 + kq;

  f32x4 acc[4][4];
#pragma unroll
  for (int m = 0; m < 4; ++m)
#pragma unroll
    for (int n = 0; n < 4; ++n) acc[m][n] = (f32x4){0.f, 0.f, 0.f, 0.f};

  const __hip_bfloat16* ga = A + (size_t)(m0 + w * 32 + srow) * K + scol;
  const __hip_bfloat16* gb = Bt + (size_t)(n0 + w * 32 + srow) * K + scol;
  __hip_bfloat16* la0 = &As[(w * 32) * 32];
  __hip_bfloat16* la1 = &As[(w * 32 + 16) * 32];
  __hip_bfloat16* lb0 = &Bs[(w * 32) * 32];
  __hip_bfloat16* lb1 = &Bs[(w * 32 + 16) * 32];

  for (int k0 = 0; k0 < K; k0 += 32) {
    gll16(ga + k0, la0);
    gll16(ga + (size_t)16 * K + k0, la1);
    gll16(gb + k0, lb0);
    gll16(gb + (size_t)16 * K + k0, lb1);
    __syncthreads();
    bf16x8 af[4], bfv[4];
#pragma unroll
    for (int m = 0; m < 4; ++m) af[m] = *(const bf16x8*)&As[aidx[m]];
#pragma unroll
    for (int n = 0; n < 4; ++n) bfv[n] = *(const bf16x8*)&Bs[bidx[n]];
#pragma unroll
    for (int m = 0; m < 4; ++m)
#pragma unroll
      for (int n = 0; n < 4; ++n)
        acc[m][n] = __builtin_amdgcn_mfma_f32_16x16x32_bf16(af[m], bfv[n], acc[m][n], 0, 0, 0);
    __syncthreads();
  }

#pragma unroll
  for (int m = 0; m < 4; ++m) {
#pragma unroll
    for (int n = 0; n < 4; ++n) {
#pragma unroll
      for (int r = 0; r < 4; ++r) {
        const int row = m0 + wr * 64 + m * 16 + (lane >> 4) * 4 + r;
        const int col = n0 + wc * 64 + n * 16 + (lane & 15);
        float v = acc[m][n][r];
        if (EPI == 1) v = gelu_f(v);
        if (EPI == 2) v += R[(size_t)row * N + col];
        if (OBF) Cb[(size_t)row * N + col] = __float2bfloat16(v);
        else C[(size_t)row * N + col] = v;
      }
    }
  }
}

// ---------------- grouped MoE bf16 MFMA GEMM over expert-sorted slots ----------
// EPI: 1 = gelu -> bf16 out (up proj), 3 = gate-scale -> fp32 out (down proj)
template <int EPI>
__global__ __launch_bounds__(256) void k_mgemm_moe(const __hip_bfloat16* __restrict__ A,
                                                   const __hip_bfloat16* __restrict__ Btbase,
                                                   float* __restrict__ C,
                                                   __hip_bfloat16* __restrict__ Cb,
                                                   const int* __restrict__ tile_e,
                                                   const int* __restrict__ tile_r0,
                                                   const int* __restrict__ ntiles,
                                                   const int* __restrict__ counts,
                                                   const int* __restrict__ offs,
                                                   const int* __restrict__ row_slot,
                                                   const float* __restrict__ gate_slot,
                                                   int N, int K, int gather) {
  const int tile = blockIdx.y;
  if (tile >= *ntiles) return;
  const int e = tile_e[tile], r0 = tile_r0[tile];
  const int cnt = counts[e], off = offs[e];
  const __hip_bfloat16* Bt = Btbase + (size_t)e * N * K;

  __shared__ __hip_bfloat16 As[128 * 32];
  __shared__ __hip_bfloat16 Bs[128 * 32];
  const int tid = threadIdx.x;
  const int w = tid >> 6, lane = tid & 63;
  const int wr = w >> 1, wc = w & 1;
  const int n0 = blockIdx.x << 7;
  const int srow = lane >> 2;
  const int scol = (lane & 3) * 8;
  const int kq = (lane >> 4) * 8;
  int aidx[4], bidx[4];
#pragma unroll
  for (int m = 0; m < 4; ++m) aidx[m] = (wr * 64 + m * 16 + (lane & 15)) * 32 + kq;
#pragma unroll
  for (int n = 0; n < 4; ++n) bidx[n] = (wc * 64 + n * 16 + (lane & 15)) * 32 + kq;

  // gather rows (clamped; invalid rows masked in epilogue)
  const int last = off + cnt - 1;
  int s0 = off + r0 + w * 32 + srow;        if (s0 > last) s0 = last;
  int s1 = off + r0 + w * 32 + 16 + srow;   if (s1 > last) s1 = last;
  const int arow0 = gather ? row_slot[s0] : s0;
  const int arow1 = gather ? row_slot[s1] : s1;

  f32x4 acc[4][4];
#pragma unroll
  for (int m = 0; m < 4; ++m)
#pragma unroll
    for (int n = 0; n < 4; ++n) acc[m][n] = (f32x4){0.f, 0.f, 0.f, 0.f};

  const __hip_bfloat16* ga0 = A + (size_t)arow0 * K + scol;
  const __hip_bfloat16* ga1 = A + (size_t)arow1 * K + scol;
  const __hip_bfloat16* gb = Bt + (size_t)(n0 + w * 32 + srow) * K + scol;
  __hip_bfloat16* la0 = &As[(w * 32) * 32];
  __hip_bfloat16* la1 = &As[(w * 32 + 16) * 32];
  __hip_bfloat16* lb0 = &Bs[(w * 32) * 32];
  __hip_bfloat16* lb1 = &Bs[(w * 32 + 16) * 32];

  for (int k0 = 0; k0 < K; k0 += 32) {
    gll16(ga0 + k0, la0);
    gll16(ga1 + k0, la1);
    gll16(gb + k0, lb0);
    gll16(gb + (size_t)16 * K + k0, lb1);
    __syncthreads();
    bf16x8 af[4], bfv[4];
#pragma unroll
    for (int m = 0; m < 4; ++m) af[m] = *(const bf16x8*)&As[aidx[m]];
#pragma unroll
    for (int n = 0; n < 4; ++n) bfv[n] = *(const bf16x8*)&Bs[bidx[n]];
#pragma unroll
    for (int m = 0; m < 4; ++m)
#pragma unroll
      for (int n = 0; n < 4; ++n)
        acc[m][n] = __builtin_amdgcn_mfma_f32_16x16x32_bf16(af[m], bfv[n], acc[m][n], 0, 0, 0);
    __syncthreads();
  }

#pragma unroll
  for (int m = 0; m < 4; ++m) {
#pragma unroll
    for (int r = 0; r < 4; ++r) {
      const int rl = wr * 64 + m * 16 + (lane >> 4) * 4 + r;
      if (r0 + rl < cnt) {
        const int slot = off + r0 + rl;
        const float sc = (EPI == 3) ? gate_slot[slot] : 1.0f;
#pragma unroll
        for (int n = 0; n < 4; ++n) {
          const int col = n0 + wc * 64 + n * 16 + (lane & 15);
          float v = acc[m][n][r];
          if (EPI == 1) {
            Cb[(size_t)slot * N + col] = __float2bfloat16(gelu_f(v));
          } else {
            C[(size_t)slot * N + col] = v * sc;
          }
        }
      }
    }
  }
}

// ---------------- flash attention, fp32, 64x64 tiles ----------------
// qkv layout per token row (3072): [q(16 heads x 64) | k | v]; y out is bf16
__global__ __launch_bounds__(256) void k_attn(const float* __restrict__ qkv,
                                              __hip_bfloat16* __restrict__ y) {
  const int bh = blockIdx.x;
  const int qt = blockIdx.y;
  const int b = bh >> 4, hh = bh & 15;
  const int tid = threadIdx.x;
  const int r = tid & 63, g = tid >> 6;
  __shared__ float Qs[64][65];
  __shared__ float Ks[64][65];
  __shared__ float Vs[64][65];
  __shared__ float Ps[64][65];
  __shared__ float wred[4][64];
  __shared__ float rowm[64], rowl[64];
  const size_t base = (size_t)b * 1024 * 3072;
  for (int i = tid; i < 64 * 16; i += 256) {
    int rr = i >> 4, dq = (i & 15) * 4;
    float4 v = *(const float4*)(qkv + base + (size_t)(qt * 64 + rr) * 3072 + hh * 64 + dq);
    Qs[rr][dq] = v.x; Qs[rr][dq + 1] = v.y; Qs[rr][dq + 2] = v.z; Qs[rr][dq + 3] = v.w;
  }
  if (g == 0) { rowm[r] = -INFINITY; rowl[r] = 0.0f; }
  float yacc[16];
#pragma unroll
  for (int i = 0; i < 16; ++i) yacc[i] = 0.0f;
  const int qg = qt * 64 + r;
  for (int kt = 0; kt <= qt; ++kt) {
    __syncthreads();
    for (int i = tid; i < 64 * 16; i += 256) {
      int rr = i >> 4, dq = (i & 15) * 4;
      float4 kv = *(const float4*)(qkv + base + (size_t)(kt * 64 + rr) * 3072 + 1024 + hh * 64 + dq);
      Ks[rr][dq] = kv.x; Ks[rr][dq + 1] = kv.y; Ks[rr][dq + 2] = kv.z; Ks[rr][dq + 3] = kv.w;
      float4 vv = *(const float4*)(qkv + base + (size_t)(kt * 64 + rr) * 3072 + 2048 + hh * 64 + dq);
      Vs[rr][dq] = vv.x; Vs[rr][dq + 1] = vv.y; Vs[rr][dq + 2] = vv.z; Vs[rr][dq + 3] = vv.w;
    }
    __syncthreads();
    float s[16];
    float tmax = -INFINITY;
#pragma unroll 4
    for (int jj = 0; jj < 16; ++jj) {
      const int j = g * 16 + jj;
      float acc = 0.0f;
#pragma unroll
      for (int d = 0; d < 64; ++d) acc += Qs[r][d] * Ks[j][d];
      acc *= 0.125f;
      if (kt * 64 + j > qg) acc = -INFINITY;
      s[jj] = acc;
      tmax = fmaxf(tmax, acc);
    }
    wred[g][r] = tmax;
    __syncthreads();
    const float mt = fmaxf(fmaxf(wred[0][r], wred[1][r]), fmaxf(wred[2][r], wred[3][r]));
    const float mold = rowm[r];
    const float mnew = fmaxf(mold, mt);
    const float factor = __expf(mold - mnew);
    __syncthreads();
    float tsum = 0.0f;
#pragma unroll
    for (int jj = 0; jj < 16; ++jj) {
      float p = __expf(s[jj] - mnew);
      Ps[r][g * 16 + jj] = p;
      tsum += p;
    }
    wred[g][r] = tsum;
#pragma unroll
    for (int dd = 0; dd < 16; ++dd) yacc[dd] *= factor;
    __syncthreads();
    if (g == 0) {
      rowl[r] = rowl[r] * factor + wred[0][r] + wred[1][r] + wred[2][r] + wred[3][r];
      rowm[r] = mnew;
    }
#pragma unroll 8
    for (int j = 0; j < 64; ++j) {
      const float p = Ps[r][j];
#pragma unroll
      for (int dd = 0; dd < 16; ++dd) yacc[dd] += p * Vs[j][g * 16 + dd];
    }
  }
  __syncthreads();
  const float inv = 1.0f / rowl[r];
  __hip_bfloat16* yo = y + (size_t)(b * 1024 + qt * 64 + r) * HD + hh * 64 + g * 16;
  union { bf16x8 v; __hip_bfloat16 h[8]; } u0, u1;
#pragma unroll
  for (int i = 0; i < 8; ++i) u0.h[i] = __float2bfloat16(yacc[i] * inv);
#pragma unroll
  for (int i = 0; i < 8; ++i) u1.h[i] = __float2bfloat16(yacc[8 + i] * inv);
  *(bf16x8*)yo = u0.v;
  *(bf16x8*)(yo + 8) = u1.v;
}

// ---------------- router: softmax(x@Wr), top-3, counts (all fp32) -------------
__global__ __launch_bounds__(64) void k_router(const float* __restrict__ xln,
                                               const float* __restrict__ Wr,
                                               float* __restrict__ gates,
                                               int* __restrict__ eidx,
                                               int* __restrict__ counts) {
  const int t = blockIdx.x;
  const int lane = threadIdx.x;
  const float* xr = xln + (size_t)t * HD;
  float partial[NEXP];
#pragma unroll
  for (int e = 0; e < NEXP; ++e) partial[e] = 0.f;
  for (int k = lane; k < HD; k += 64) {
    const float xv = xr[k];
    const float* wrow = Wr + (size_t)k * NEXP;
#pragma unroll
    for (int e = 0; e < NEXP; ++e) partial[e] += xv * wrow[e];
  }
  __shared__ float lg[NEXP];
#pragma unroll
  for (int e = 0; e < NEXP; ++e) {
    float v = partial[e];
#pragma unroll
    for (int o = 32; o > 0; o >>= 1) v += __shfl_down(v, o);
    if (lane == 0) lg[e] = v;
  }
  __syncthreads();
  if (lane == 0) {
    float m = lg[0];
#pragma unroll
    for (int e = 1; e < NEXP; ++e) m = fmaxf(m, lg[e]);
    float p[NEXP], sum = 0.f;
#pragma unroll
    for (int e = 0; e < NEXP; ++e) { p[e] = __expf(lg[e] - m); sum += p[e]; }
    const float isum = 1.0f / sum;
#pragma unroll
    for (int e = 0; e < NEXP; ++e) p[e] *= isum;
    bool used[NEXP] = {};
    for (int k = 0; k < TOPKE; ++k) {
      int best = -1; float bv = -1.f;
      for (int e = 0; e < NEXP; ++e)
        if (!used[e] && p[e] > bv) { bv = p[e]; best = e; }
      used[best] = true;
      eidx[t * TOPKE + k] = best;
      gates[t * TOPKE + k] = bv;
      atomicAdd(&counts[best], 1);
    }
  }
}

__global__ void k_zero(int* p) { if (threadIdx.x < 16) p[threadIdx.x] = 0; }

__global__ void k_prefix(const int* __restrict__ counts, int* __restrict__ offs,
                         int* __restrict__ cursor, int* __restrict__ tile_e,
                         int* __restrict__ tile_r0, int* __restrict__ ntiles) {
  if (threadIdx.x == 0 && blockIdx.x == 0) {
    int off = 0, nt = 0;
    for (int e = 0; e < NEXP; ++e) {
      offs[e] = off; cursor[e] = off;
      const int c = counts[e];
      for (int r0 = 0; r0 < c; r0 += 128) { tile_e[nt] = e; tile_r0[nt] = r0; ++nt; }
      off += c;
    }
    *ntiles = nt;
  }
}

__global__ __launch_bounds__(256) void k_scatter(const int* __restrict__ eidx,
                                                 const float* __restrict__ gates,
                                                 int* __restrict__ cursor,
                                                 int* __restrict__ row_slot,
                                                 float* __restrict__ gate_slot,
                                                 int* __restrict__ slot_of) {
  const int i = blockIdx.x * blockDim.x + threadIdx.x;
  if (i >= NSLOT) return;
  const int e = eidx[i];
  const int pos = atomicAdd(&cursor[e], 1);
  row_slot[pos] = i / TOPKE;
  gate_slot[pos] = gates[i];
  slot_of[i] = pos;
}

// ---------------- combine: h += shared + sum_k routed_down[slot] ----------------
__global__ __launch_bounds__(256) void k_combine(float* __restrict__ h,
                                                 const float* __restrict__ sh,
                                                 const float* __restrict__ rd,
                                                 const int* __restrict__ slot_of) {
  const int t = blockIdx.x;
  const int s0 = slot_of[t * 3 + 0], s1 = slot_of[t * 3 + 1], s2 = slot_of[t * 3 + 2];
  const float4* shp = (const float4*)(sh + (size_t)t * HD);
  const float4* r0 = (const float4*)(rd + (size_t)s0 * HD);
  const float4* r1 = (const float4*)(rd + (size_t)s1 * HD);
  const float4* r2 = (const float4*)(rd + (size_t)s2 * HD);
  float4* hp = (float4*)(h + (size_t)t * HD);
  const int i = threadIdx.x;
  float4 hv = hp[i], a = shp[i], b0 = r0[i], b1 = r1[i], b2 = r2[i];
  hv.x += a.x + b0.x + b1.x + b2.x;
  hv.y += a.y + b0.y + b1.y + b2.y;
  hv.z += a.z + b0.z + b1.z + b2.z;
  hv.w += a.w + b0.w + b1.w + b2.w;
  hp[i] = hv;
}

// ---------------- tied head: logits[b][v] = dot(hf[b], Wemb[v]) ----------------
__global__ __launch_bounds__(256) void k_head(const float* __restrict__ hf,
                                              const float* __restrict__ Wemb,
                                              float* __restrict__ out) {
  __shared__ float hs[4][HD];
  const int tid = threadIdx.x;
  for (int i = tid; i < HD; i += 256) {
    hs[0][i] = hf[i]; hs[1][i] = hf[HD + i];
    hs[2][i] = hf[2 * HD + i]; hs[3][i] = hf[3 * HD + i];
  }
  __syncthreads();
  const int w = tid >> 6, lane = tid & 63;
  for (int i = 0; i < 4; ++i) {
    const int v = blockIdx.x * 16 + w * 4 + i;
    const float4* wr = (const float4*)(Wemb + (size_t)v * HD);
    float a0 = 0.f, a1 = 0.f, a2 = 0.f, a3 = 0.f;
    for (int q = lane; q < HD / 4; q += 64) {
      float4 wv = wr[q];
      const int k = q * 4;
      a0 += wv.x * hs[0][k] + wv.y * hs[0][k + 1] + wv.z * hs[0][k + 2] + wv.w * hs[0][k + 3];
      a1 += wv.x * hs[1][k] + wv.y * hs[1][k + 1] + wv.z * hs[1][k + 2] + wv.w * hs[1][k + 3];
      a2 += wv.x * hs[2][k] + wv.y * hs[2][k + 1] + wv.z * hs[2][k + 2] + wv.w * hs[2][k + 3];
      a3 += wv.x * hs[3][k] + wv.y * hs[3][k + 1] + wv.z * hs[3][k + 2] + wv.w * hs[3][k + 3];
    }
#pragma unroll
    for (int o = 32; o > 0; o >>= 1) {
      a0 += __shfl_down(a0, o); a1 += __shfl_down(a1, o);
      a2 += __shfl_down(a2, o); a3 += __shfl_down(a3, o);
    }
    if (lane == 0) {
      out[v] = a0; out[NVOCAB + v] = a1;
      out[2 * NVOCAB + v] = a2; out[3 * NVOCAB + v] = a3;
    }
  }
}

extern "C" void kernel_launch(void* const* d_in, const int* in_sizes, int n_in,
                              void* d_out, int out_size, void* d_ws, size_t ws_size,
                              hipStream_t stream) {
  (void)in_sizes; (void)n_in; (void)out_size; (void)ws_size;
  const int* x = (const int*)d_in[0];
  const float* W_emb = (const float*)d_in[1];
  const float* W_pos = (const float*)d_in[2];
  const float* ln1_g = (const float*)d_in[3];
  const float* ln1_b = (const float*)d_in[4];
  const float* Wqkv = (const float*)d_in[5];
  const float* Wo = (const float*)d_in[6];
  const float* ln2_g = (const float*)d_in[7];
  const float* ln2_b = (const float*)d_in[8];
  const float* Wr = (const float*)d_in[9];
  const float* Wsu = (const float*)d_in[10];
  const float* Wsd = (const float*)d_in[11];
  const float* Wu = (const float*)d_in[12];
  const float* Wd = (const float*)d_in[13];
  const float* lnf_g = (const float*)d_in[14];
  const float* lnf_b = (const float*)d_in[15];
  float* out = (float*)d_out;

  float* wsf = (float*)d_ws;
  size_t o = 0;
  float* hbuf = wsf + o; o += (size_t)BT * HD;
  float* lno  = wsf + o; o += (size_t)BT * HD;
  float* qkvb = wsf + o; o += (size_t)BT * 3 * HD;    // also routed_down
  float* ab   = wsf + o; o += (size_t)BT * HD;
  float* moe_out = wsf + o; o += (size_t)BT * HD;
  float* hf = wsf + o; o += 4 * HD;
  float* gates = wsf + o; o += NSLOT;
  float* gate_slot = wsf + o; o += NSLOT;
  int* eidx = (int*)(wsf + o); o += NSLOT;
  int* row_slot = (int*)(wsf + o); o += NSLOT;
  int* slot_of = (int*)(wsf + o); o += NSLOT;
  int* counts = (int*)(wsf + o); o += 16;
  int* offs = (int*)(wsf + o); o += 16;
  int* cursor = (int*)(wsf + o); o += 16;
  int* tile_e = (int*)(wsf + o); o += 256;
  int* tile_r0 = (int*)(wsf + o); o += 256;
  int* ntiles = (int*)(wsf + o); o += 16;
  // bf16 regions (2 bf16 per float slot)
  __hip_bfloat16* lno_bf = (__hip_bfloat16*)(wsf + o); o += (size_t)BT * HD / 2;
  __hip_bfloat16* ybf    = (__hip_bfloat16*)(wsf + o); o += (size_t)BT * HD / 2;
  __hip_bfloat16* shm_bf = (__hip_bfloat16*)(wsf + o); o += (size_t)BT * ED / 2;
  __hip_bfloat16* rup_bf = (__hip_bfloat16*)(wsf + o); o += (size_t)NSLOT * ED / 2;
  __hip_bfloat16* wqkv_t = (__hip_bfloat16*)(wsf + o); o += (size_t)NLAYER * HD * 3 * HD / 2;
  __hip_bfloat16* wo_t   = (__hip_bfloat16*)(wsf + o); o += (size_t)NLAYER * HD * HD / 2;
  __hip_bfloat16* wsu_t  = (__hip_bfloat16*)(wsf + o); o += (size_t)NLAYER * HD * ED / 2;
  __hip_bfloat16* wsd_t  = (__hip_bfloat16*)(wsf + o); o += (size_t)NLAYER * ED * HD / 2;
  __hip_bfloat16* wu_t   = (__hip_bfloat16*)(wsf + o); o += (size_t)NLAYER * NEXP * HD * ED / 2;
  __hip_bfloat16* wd_t   = (__hip_bfloat16*)(wsf + o); o += (size_t)NLAYER * NEXP * ED * HD / 2;
  float* routed_down = qkvb;

  // weight transpose+convert: [z][K][N] fp32 -> [z][N][K] bf16
  dim3 tb(32, 8);
  k_wtrans<<<dim3(3 * HD / 32, HD / 32, NLAYER), tb, 0, stream>>>(Wqkv, wqkv_t, HD, 3 * HD);
  k_wtrans<<<dim3(HD / 32, HD / 32, NLAYER), tb, 0, stream>>>(Wo, wo_t, HD, HD);
  k_wtrans<<<dim3(ED / 32, HD / 32, NLAYER), tb, 0, stream>>>(Wsu, wsu_t, HD, ED);
  k_wtrans<<<dim3(HD / 32, ED / 32, NLAYER), tb, 0, stream>>>(Wsd, wsd_t, ED, HD);
  k_wtrans<<<dim3(ED / 32, HD / 32, NLAYER * NEXP), tb, 0, stream>>>(Wu, wu_t, HD, ED);
  k_wtrans<<<dim3(HD / 32, ED / 32, NLAYER * NEXP), tb, 0, stream>>>(Wd, wd_t, ED, HD);

  k_embed<<<BT, 256, 0, stream>>>(x, W_emb, W_pos, hbuf);

  for (int l = 0; l < NLAYER; ++l) {
    k_ln<<<BT, 256, 0, stream>>>(hbuf, ln1_g + (size_t)l * HD, ln1_b + (size_t)l * HD,
                                 lno, lno_bf);
    k_mgemm<0, 0><<<dim3(24, 32), 256, 0, stream>>>(
        lno_bf, wqkv_t + (size_t)l * HD * 3 * HD, nullptr, qkvb, nullptr, BT, 3 * HD, HD);
    k_attn<<<dim3(64, 16), 256, 0, stream>>>(qkvb, ybf);
    k_mgemm<2, 0><<<dim3(8, 32), 256, 0, stream>>>(
        ybf, wo_t + (size_t)l * HD * HD, hbuf, ab, nullptr, BT, HD, HD);
    k_ln<<<BT, 256, 0, stream>>>(ab, ln2_g + (size_t)l * HD, ln2_b + (size_t)l * HD,
                                 lno, lno_bf);
    k_zero<<<1, 64, 0, stream>>>(counts);
    k_router<<<BT, 64, 0, stream>>>(lno, Wr + (size_t)l * HD * NEXP, gates, eidx, counts);
    k_prefix<<<1, 1, 0, stream>>>(counts, offs, cursor, tile_e, tile_r0, ntiles);
    k_scatter<<<(NSLOT + 255) / 256, 256, 0, stream>>>(eidx, gates, cursor, row_slot,
                                                       gate_slot, slot_of);
    // shared expert
    k_mgemm<1, 1><<<dim3(4, 32), 256, 0, stream>>>(
        lno_bf, wsu_t + (size_t)l * HD * ED, nullptr, nullptr, shm_bf, BT, ED, HD);
    k_mgemm<0, 0><<<dim3(8, 32), 256, 0, stream>>>(
        shm_bf, wsd_t + (size_t)l * ED * HD, nullptr, moe_out, nullptr, BT, HD, ED);
    // routed experts (top-3 only)
    k_mgemm_moe<1><<<dim3(4, 112), 256, 0, stream>>>(
        lno_bf, wu_t + (size_t)l * NEXP * HD * ED, nullptr, rup_bf,
        tile_e, tile_r0, ntiles, counts, offs, row_slot, gate_slot, ED, HD, 1);
    k_mgemm_moe<3><<<dim3(8, 112), 256, 0, stream>>>(
        rup_bf, wd_t + (size_t)l * NEXP * ED * HD, routed_down, nullptr,
        tile_e, tile_r0, ntiles, counts, offs, row_slot, gate_slot, HD, ED, 0);
    k_combine<<<BT, 256, 0, stream>>>(hbuf, moe_out, routed_down, slot_of);
  }

  k_lnf<<<4, 256, 0, stream>>>(hbuf, lnf_g, lnf_b, hf);
  k_head<<<NVOCAB / 16, 256, 0, stream>>>(hf, W_emb, out);
}

// Round 3
// 2333.558 us; speedup vs baseline: 2.8697x; 1.4826x over previous
//
#include <hip/hip_runtime.h>
#include <hip/hip_bf16.h>
#include <math.h>

#define BT 4096      // B*T tokens
#define HD 1024      // hidden
#define NHEAD 16
#define DH 64
#define ED 512       // expert dim
#define NEXP 10
#define TOPKE 3
#define NLAYER 4
#define NVOCAB 32000
#define NSLOT (BT * TOPKE)   // 12288

typedef __attribute__((ext_vector_type(8))) short bf16x8;
typedef __attribute__((ext_vector_type(4))) short bf16x4;
typedef __attribute__((ext_vector_type(4))) float f32x4;

__device__ __forceinline__ float gelu_f(float x) {
  return 0.5f * x * (1.0f + erff(x * 0.70710678118654752440f));
}

// async global->LDS, 16B per lane, 64 lanes = 1KB per call.
__device__ __forceinline__ void gll16(const void* g, void* l) {
  __builtin_amdgcn_global_load_lds(
      (const __attribute__((address_space(1))) unsigned int*)g,
      (__attribute__((address_space(3))) unsigned int*)l, 16, 0, 0);
}

// ---------------- embedding: h = W_emb[x] + W_pos[pos] ----------------
__global__ __launch_bounds__(256) void k_embed(const int* __restrict__ x,
                                               const float* __restrict__ Wemb,
                                               const float* __restrict__ Wpos,
                                               float* __restrict__ h) {
  const int t = blockIdx.x;
  const int pos = t & 1023;
  const int tok = x[t];
  const float4* we = (const float4*)(Wemb + (size_t)tok * HD);
  const float4* wp = (const float4*)(Wpos + (size_t)pos * HD);
  float4* ho = (float4*)(h + (size_t)t * HD);
  const int i = threadIdx.x;
  float4 a = we[i], b = wp[i];
  ho[i] = make_float4(a.x + b.x, a.y + b.y, a.z + b.z, a.w + b.w);
}

// ---------------- weight transpose + fp32->bf16: in [z][K][N] -> out [z][N][K]
__global__ __launch_bounds__(256) void k_wtrans(const float* __restrict__ in,
                                                __hip_bfloat16* __restrict__ out,
                                                int K, int N) {
  const int z = blockIdx.z;
  const float* src = in + (size_t)z * K * N;
  __hip_bfloat16* dst = out + (size_t)z * N * K;
  __shared__ float t[32][33];
  const int tx = threadIdx.x, ty = threadIdx.y;    // (32, 8)
  const int k0 = blockIdx.y * 32, n0 = blockIdx.x * 32;
  for (int r = ty; r < 32; r += 8) t[r][tx] = src[(size_t)(k0 + r) * N + n0 + tx];
  __syncthreads();
  for (int r = ty; r < 32; r += 8)
    dst[(size_t)(n0 + r) * K + k0 + tx] = __float2bfloat16(t[tx][r]);
}

// ---------------- V transpose per (b,h): qkv V part -> vt[(bh*64+d)][1024 t] --
__global__ __launch_bounds__(256) void k_vtrans(const __hip_bfloat16* __restrict__ qkv,
                                                __hip_bfloat16* __restrict__ vt) {
  const int bh = blockIdx.x, tt = blockIdx.y;
  const int b = bh >> 4, h = bh & 15;
  __shared__ __hip_bfloat16 t[64][72];
  for (int c = threadIdx.x; c < 512; c += 256) {
    int r = c >> 3, d0 = (c & 7) * 8;
    *(bf16x8*)&t[r][d0] =
        *(const bf16x8*)(qkv + ((size_t)(b * 1024 + tt * 64 + r)) * 3072 + 2048 + h * 64 + d0);
  }
  __syncthreads();
  for (int c = threadIdx.x; c < 512; c += 256) {
    int d = c >> 3, t0 = (c & 7) * 8;
    union { bf16x8 v; __hip_bfloat16 e[8]; } u;
#pragma unroll
    for (int j = 0; j < 8; ++j) u.e[j] = t[t0 + j][d];
    *(bf16x8*)(vt + ((size_t)(bh * 64 + d)) * 1024 + tt * 64 + t0) = u.v;
  }
}

// ---------------- layernorm over rows of HD: fp32 + bf16 outputs ----------------
__global__ __launch_bounds__(256) void k_ln(const float* __restrict__ in,
                                            const float* __restrict__ g,
                                            const float* __restrict__ b,
                                            float* __restrict__ outf,
                                            __hip_bfloat16* __restrict__ outb) {
  const int row = blockIdx.x;
  const int tid = threadIdx.x;
  const float* xr = in + (size_t)row * HD;
  float s = 0.f, ss = 0.f;
  for (int i = tid; i < HD; i += 256) { float v = xr[i]; s += v; ss += v * v; }
#pragma unroll
  for (int o = 32; o > 0; o >>= 1) { s += __shfl_down(s, o); ss += __shfl_down(ss, o); }
  __shared__ float rs[4], rss[4];
  if ((tid & 63) == 0) { rs[tid >> 6] = s; rss[tid >> 6] = ss; }
  __syncthreads();
  const float S = rs[0] + rs[1] + rs[2] + rs[3];
  const float SS = rss[0] + rss[1] + rss[2] + rss[3];
  const float mean = S * (1.0f / HD);
  const float var = SS * (1.0f / HD) - mean * mean;
  const float inv = rsqrtf(var + 1e-5f);
  float* orow = outf + (size_t)row * HD;
  __hip_bfloat16* brow = outb + (size_t)row * HD;
  for (int i = tid; i < HD; i += 256) {
    float v = (xr[i] - mean) * inv * g[i] + b[i];
    orow[i] = v;
    brow[i] = __float2bfloat16(v);
  }
}

// final LN over the 4 last-token rows only
__global__ __launch_bounds__(256) void k_lnf(const float* __restrict__ h,
                                             const float* __restrict__ g,
                                             const float* __restrict__ b,
                                             float* __restrict__ hf) {
  const int row = blockIdx.x * 1024 + 1023;
  const int tid = threadIdx.x;
  const float* xr = h + (size_t)row * HD;
  float s = 0.f, ss = 0.f;
  for (int i = tid; i < HD; i += 256) { float v = xr[i]; s += v; ss += v * v; }
#pragma unroll
  for (int o = 32; o > 0; o >>= 1) { s += __shfl_down(s, o); ss += __shfl_down(ss, o); }
  __shared__ float rs[4], rss[4];
  if ((tid & 63) == 0) { rs[tid >> 6] = s; rss[tid >> 6] = ss; }
  __syncthreads();
  const float S = rs[0] + rs[1] + rs[2] + rs[3];
  const float SS = rss[0] + rss[1] + rss[2] + rss[3];
  const float mean = S * (1.0f / HD);
  const float var = SS * (1.0f / HD) - mean * mean;
  const float inv = rsqrtf(var + 1e-5f);
  float* orow = hf + (size_t)blockIdx.x * HD;
  for (int i = tid; i < HD; i += 256) {
    float v = xr[i];
    orow[i] = (v - mean) * inv * g[i] + b[i];
  }
}

// ---------------- bf16 MFMA GEMM: C[M,N] = A[M,K] @ Bt[N,K]^T ----------------
template <int EPI, int OBF>
__global__ __launch_bounds__(256) void k_mgemm(const __hip_bfloat16* __restrict__ A,
                                               const __hip_bfloat16* __restrict__ Bt,
                                               const float* __restrict__ R,
                                               float* __restrict__ C,
                                               __hip_bfloat16* __restrict__ Cb,
                                               int M, int N, int K) {
  __shared__ __hip_bfloat16 As[128 * 32];
  __shared__ __hip_bfloat16 Bs[128 * 32];
  const int tid = threadIdx.x;
  const int w = tid >> 6, lane = tid & 63;
  const int wr = w >> 1, wc = w & 1;
  const int m0 = blockIdx.y << 7, n0 = blockIdx.x << 7;
  const int srow = lane >> 2;
  const int scol = (lane & 3) * 8;
  const int kq = (lane >> 4) * 8;
  int aidx[4], bidx[4];
#pragma unroll
  for (int m = 0; m < 4; ++m) aidx[m] = (wr * 64 + m * 16 + (lane & 15)) * 32 + kq;
#pragma unroll
  for (int n = 0; n < 4; ++n) bidx[n] = (wc * 64 + n * 16 + (lane & 15)) * 32 + kq;

  f32x4 acc[4][4];
#pragma unroll
  for (int m = 0; m < 4; ++m)
#pragma unroll
    for (int n = 0; n < 4; ++n) acc[m][n] = (f32x4){0.f, 0.f, 0.f, 0.f};

  const __hip_bfloat16* ga = A + (size_t)(m0 + w * 32 + srow) * K + scol;
  const __hip_bfloat16* gb = Bt + (size_t)(n0 + w * 32 + srow) * K + scol;
  __hip_bfloat16* la0 = &As[(w * 32) * 32];
  __hip_bfloat16* la1 = &As[(w * 32 + 16) * 32];
  __hip_bfloat16* lb0 = &Bs[(w * 32) * 32];
  __hip_bfloat16* lb1 = &Bs[(w * 32 + 16) * 32];

  for (int k0 = 0; k0 < K; k0 += 32) {
    gll16(ga + k0, la0);
    gll16(ga + (size_t)16 * K + k0, la1);
    gll16(gb + k0, lb0);
    gll16(gb + (size_t)16 * K + k0, lb1);
    __syncthreads();
    bf16x8 af[4], bfv[4];
#pragma unroll
    for (int m = 0; m < 4; ++m) af[m] = *(const bf16x8*)&As[aidx[m]];
#pragma unroll
    for (int n = 0; n < 4; ++n) bfv[n] = *(const bf16x8*)&Bs[bidx[n]];
#pragma unroll
    for (int m = 0; m < 4; ++m)
#pragma unroll
      for (int n = 0; n < 4; ++n)
        acc[m][n] = __builtin_amdgcn_mfma_f32_16x16x32_bf16(af[m], bfv[n], acc[m][n], 0, 0, 0);
    __syncthreads();
  }

#pragma unroll
  for (int m = 0; m < 4; ++m) {
#pragma unroll
    for (int n = 0; n < 4; ++n) {
#pragma unroll
      for (int r = 0; r < 4; ++r) {
        const int row = m0 + wr * 64 + m * 16 + (lane >> 4) * 4 + r;
        const int col = n0 + wc * 64 + n * 16 + (lane & 15);
        float v = acc[m][n][r];
        if (EPI == 1) v = gelu_f(v);
        if (EPI == 2) v += R[(size_t)row * N + col];
        if (OBF) Cb[(size_t)row * N + col] = __float2bfloat16(v);
        else C[(size_t)row * N + col] = v;
      }
    }
  }
}

// ---------------- grouped MoE bf16 MFMA GEMM over expert-sorted slots ----------
template <int EPI>
__global__ __launch_bounds__(256) void k_mgemm_moe(const __hip_bfloat16* __restrict__ A,
                                                   const __hip_bfloat16* __restrict__ Btbase,
                                                   float* __restrict__ C,
                                                   __hip_bfloat16* __restrict__ Cb,
                                                   const int* __restrict__ tile_e,
                                                   const int* __restrict__ tile_r0,
                                                   const int* __restrict__ ntiles,
                                                   const int* __restrict__ counts,
                                                   const int* __restrict__ offs,
                                                   const int* __restrict__ row_slot,
                                                   const float* __restrict__ gate_slot,
                                                   int N, int K, int gather) {
  const int tile = blockIdx.y;
  if (tile >= *ntiles) return;
  const int e = tile_e[tile], r0 = tile_r0[tile];
  const int cnt = counts[e], off = offs[e];
  const __hip_bfloat16* Bt = Btbase + (size_t)e * N * K;

  __shared__ __hip_bfloat16 As[128 * 32];
  __shared__ __hip_bfloat16 Bs[128 * 32];
  const int tid = threadIdx.x;
  const int w = tid >> 6, lane = tid & 63;
  const int wr = w >> 1, wc = w & 1;
  const int n0 = blockIdx.x << 7;
  const int srow = lane >> 2;
  const int scol = (lane & 3) * 8;
  const int kq = (lane >> 4) * 8;
  int aidx[4], bidx[4];
#pragma unroll
  for (int m = 0; m < 4; ++m) aidx[m] = (wr * 64 + m * 16 + (lane & 15)) * 32 + kq;
#pragma unroll
  for (int n = 0; n < 4; ++n) bidx[n] = (wc * 64 + n * 16 + (lane & 15)) * 32 + kq;

  const int last = off + cnt - 1;
  int s0 = off + r0 + w * 32 + srow;        if (s0 > last) s0 = last;
  int s1 = off + r0 + w * 32 + 16 + srow;   if (s1 > last) s1 = last;
  const int arow0 = gather ? row_slot[s0] : s0;
  const int arow1 = gather ? row_slot[s1] : s1;

  f32x4 acc[4][4];
#pragma unroll
  for (int m = 0; m < 4; ++m)
#pragma unroll
    for (int n = 0; n < 4; ++n) acc[m][n] = (f32x4){0.f, 0.f, 0.f, 0.f};

  const __hip_bfloat16* ga0 = A + (size_t)arow0 * K + scol;
  const __hip_bfloat16* ga1 = A + (size_t)arow1 * K + scol;
  const __hip_bfloat16* gb = Bt + (size_t)(n0 + w * 32 + srow) * K + scol;
  __hip_bfloat16* la0 = &As[(w * 32) * 32];
  __hip_bfloat16* la1 = &As[(w * 32 + 16) * 32];
  __hip_bfloat16* lb0 = &Bs[(w * 32) * 32];
  __hip_bfloat16* lb1 = &Bs[(w * 32 + 16) * 32];

  for (int k0 = 0; k0 < K; k0 += 32) {
    gll16(ga0 + k0, la0);
    gll16(ga1 + k0, la1);
    gll16(gb + k0, lb0);
    gll16(gb + (size_t)16 * K + k0, lb1);
    __syncthreads();
    bf16x8 af[4], bfv[4];
#pragma unroll
    for (int m = 0; m < 4; ++m) af[m] = *(const bf16x8*)&As[aidx[m]];
#pragma unroll
    for (int n = 0; n < 4; ++n) bfv[n] = *(const bf16x8*)&Bs[bidx[n]];
#pragma unroll
    for (int m = 0; m < 4; ++m)
#pragma unroll
      for (int n = 0; n < 4; ++n)
        acc[m][n] = __builtin_amdgcn_mfma_f32_16x16x32_bf16(af[m], bfv[n], acc[m][n], 0, 0, 0);
    __syncthreads();
  }

#pragma unroll
  for (int m = 0; m < 4; ++m) {
#pragma unroll
    for (int r = 0; r < 4; ++r) {
      const int rl = wr * 64 + m * 16 + (lane >> 4) * 4 + r;
      if (r0 + rl < cnt) {
        const int slot = off + r0 + rl;
        const float sc = (EPI == 3) ? gate_slot[slot] : 1.0f;
#pragma unroll
        for (int n = 0; n < 4; ++n) {
          const int col = n0 + wc * 64 + n * 16 + (lane & 15);
          float v = acc[m][n][r];
          if (EPI == 1) {
            Cb[(size_t)slot * N + col] = __float2bfloat16(gelu_f(v));
          } else {
            C[(size_t)slot * N + col] = v * sc;
          }
        }
      }
    }
  }
}

// ---------------- MFMA flash attention (swapped QK^T), 128 q rows / block -----
// qkv bf16 per token row (3072): [q 16x64 | k | v]; vt: [(bh*64+d)][1024 t]
__global__ __launch_bounds__(256) void k_mattn(const __hip_bfloat16* __restrict__ qkv,
                                               const __hip_bfloat16* __restrict__ vt,
                                               __hip_bfloat16* __restrict__ y) {
  const int bh = blockIdx.x;
  const int qt = 7 - (int)blockIdx.y;          // big causal blocks first
  const int b = bh >> 4, hh = bh & 15;
  const int tid = threadIdx.x;
  const int w = tid >> 6, lane = tid & 63;
  const int l15 = lane & 15, g = lane >> 4;
  const int swl = (l15 & 7) << 3;

  __shared__ __hip_bfloat16 Ks[64 * 64];
  __shared__ __hip_bfloat16 Vs[64 * 64];
  __shared__ __hip_bfloat16 Pw[2][4][16 * 64];

  // Q fragments (B operand): q = l15 (wave row w*16+l15), d = kk*32+g*8+j
  bf16x8 qf[2][2];
#pragma unroll
  for (int s = 0; s < 2; ++s) {
    const __hip_bfloat16* qp =
        qkv + ((size_t)(b * 1024 + qt * 128 + s * 64 + w * 16 + l15)) * 3072 + hh * 64 + g * 8;
    qf[s][0] = *(const bf16x8*)qp;
    qf[s][1] = *(const bf16x8*)(qp + 32);
  }

  f32x4 yacc[2][4];
#pragma unroll
  for (int s = 0; s < 2; ++s)
#pragma unroll
    for (int nt = 0; nt < 4; ++nt) yacc[s][nt] = (f32x4){0.f, 0.f, 0.f, 0.f};
  float m_s[2] = {-INFINITY, -INFINITY};
  float l_s[2] = {0.f, 0.f};
  const int qg0 = qt * 128 + w * 16 + l15;

  const int ktmax = 2 * qt + 1;
  for (int kt = 0; kt <= ktmax; ++kt) {
    __syncthreads();
    // stage K tile (rows = keys) and Vt tile (rows = dims), XOR-swizzled
#pragma unroll
    for (int c0 = 0; c0 < 512; c0 += 256) {
      const int c = c0 + tid;
      const int r = c >> 3, cc = (c & 7) * 8;
      const int sw = cc ^ ((r & 7) << 3);
      *(bf16x8*)&Ks[r * 64 + sw] =
          *(const bf16x8*)(qkv + ((size_t)(b * 1024 + kt * 64 + r)) * 3072 + 1024 + hh * 64 + cc);
      *(bf16x8*)&Vs[r * 64 + sw] =
          *(const bf16x8*)(vt + ((size_t)(bh * 64 + r)) * 1024 + kt * 64 + cc);
    }
    __syncthreads();
    // K fragments (A operand): key = m*16+l15, d = kk*32+g*8+j
    bf16x8 kf[4][2];
#pragma unroll
    for (int m = 0; m < 4; ++m) {
      const int row = m * 16 + l15;
#pragma unroll
      for (int kk = 0; kk < 2; ++kk)
        kf[m][kk] = *(const bf16x8*)&Ks[row * 64 + ((kk * 32 + g * 8) ^ swl)];
    }
    bf16x8 pa[2][2] = {};
#pragma unroll
    for (int s = 0; s < 2; ++s) {
      if (kt > 2 * qt + s) continue;         // fully masked (only s=0 at last tile)
      f32x4 st[4];
#pragma unroll
      for (int m = 0; m < 4; ++m) st[m] = (f32x4){0.f, 0.f, 0.f, 0.f};
#pragma unroll
      for (int m = 0; m < 4; ++m)
#pragma unroll
        for (int kk = 0; kk < 2; ++kk)
          st[m] = __builtin_amdgcn_mfma_f32_16x16x32_bf16(kf[m][kk], qf[s][kk], st[m], 0, 0, 0);
      const int qg = qg0 + s * 64;
      const bool dia = (kt == 2 * qt + s);
      float tmax = -INFINITY;
#pragma unroll
      for (int m = 0; m < 4; ++m)
#pragma unroll
        for (int r = 0; r < 4; ++r) {
          float v = st[m][r] * 0.125f;
          if (dia && (kt * 64 + m * 16 + g * 4 + r) > qg) v = -INFINITY;
          st[m][r] = v;
          tmax = fmaxf(tmax, v);
        }
      tmax = fmaxf(tmax, __shfl_xor(tmax, 16));
      tmax = fmaxf(tmax, __shfl_xor(tmax, 32));
      const float mnew = fmaxf(m_s[s], tmax);
      const float fac = __expf(m_s[s] - mnew);
      m_s[s] = mnew;
      float tsum = 0.f;
#pragma unroll
      for (int m = 0; m < 4; ++m)
#pragma unroll
        for (int r = 0; r < 4; ++r) {
          float p = __expf(st[m][r] - mnew);
          st[m][r] = p;
          tsum += p;
        }
      tsum += __shfl_xor(tsum, 16);
      tsum += __shfl_xor(tsum, 32);
      l_s[s] = l_s[s] * fac + tsum;
      float fq[4];
#pragma unroll
      for (int r = 0; r < 4; ++r) fq[r] = __shfl(fac, g * 4 + r);
#pragma unroll
      for (int nt = 0; nt < 4; ++nt)
#pragma unroll
        for (int r = 0; r < 4; ++r) yacc[s][nt][r] *= fq[r];
      // bounce P through per-wave swizzled LDS to reach PV A-operand layout
#pragma unroll
      for (int m = 0; m < 4; ++m) {
        union { bf16x4 v; __hip_bfloat16 e[4]; } pk;
#pragma unroll
        for (int r = 0; r < 4; ++r) pk.e[r] = __float2bfloat16(st[m][r]);
        *(bf16x4*)&Pw[s][w][l15 * 64 + ((m * 16 + g * 4) ^ swl)] = pk.v;
      }
#pragma unroll
      for (int kk = 0; kk < 2; ++kk)
        pa[s][kk] = *(const bf16x8*)&Pw[s][w][l15 * 64 + ((kk * 32 + g * 8) ^ swl)];
    }
    const bool v0 = (kt <= 2 * qt);
#pragma unroll
    for (int kk = 0; kk < 2; ++kk)
#pragma unroll
      for (int nt = 0; nt < 4; ++nt) {
        bf16x8 vf = *(const bf16x8*)&Vs[(nt * 16 + l15) * 64 + ((kk * 32 + g * 8) ^ swl)];
        if (v0) yacc[0][nt] = __builtin_amdgcn_mfma_f32_16x16x32_bf16(pa[0][kk], vf, yacc[0][nt], 0, 0, 0);
        yacc[1][nt] = __builtin_amdgcn_mfma_f32_16x16x32_bf16(pa[1][kk], vf, yacc[1][nt], 0, 0, 0);
      }
  }
  // epilogue: yacc rows q = g*4+r, cols d = nt*16+l15
#pragma unroll
  for (int s = 0; s < 2; ++s) {
    const float inv = 1.0f / l_s[s];
    float iq[4];
#pragma unroll
    for (int r = 0; r < 4; ++r) iq[r] = __shfl(inv, g * 4 + r);
#pragma unroll
    for (int r = 0; r < 4; ++r) {
      __hip_bfloat16* yp =
          y + ((size_t)(b * 1024 + qt * 128 + s * 64 + w * 16 + g * 4 + r)) * HD + hh * 64 + l15;
#pragma unroll
      for (int nt = 0; nt < 4; ++nt)
        yp[nt * 16] = __float2bfloat16(yacc[s][nt][r] * iq[r]);
    }
  }
}

// ---------------- router: softmax(x@Wr), top-3, counts (all fp32) -------------
__global__ __launch_bounds__(64) void k_router(const float* __restrict__ xln,
                                               const float* __restrict__ Wr,
                                               float* __restrict__ gates,
                                               int* __restrict__ eidx,
                                               int* __restrict__ counts) {
  const int t = blockIdx.x;
  const int lane = threadIdx.x;
  const float* xr = xln + (size_t)t * HD;
  float partial[NEXP];
#pragma unroll
  for (int e = 0; e < NEXP; ++e) partial[e] = 0.f;
  for (int k = lane; k < HD; k += 64) {
    const float xv = xr[k];
    const float* wrow = Wr + (size_t)k * NEXP;
#pragma unroll
    for (int e = 0; e < NEXP; ++e) partial[e] += xv * wrow[e];
  }
  __shared__ float lg[NEXP];
#pragma unroll
  for (int e = 0; e < NEXP; ++e) {
    float v = partial[e];
#pragma unroll
    for (int o = 32; o > 0; o >>= 1) v += __shfl_down(v, o);
    if (lane == 0) lg[e] = v;
  }
  __syncthreads();
  if (lane == 0) {
    float m = lg[0];
#pragma unroll
    for (int e = 1; e < NEXP; ++e) m = fmaxf(m, lg[e]);
    float p[NEXP], sum = 0.f;
#pragma unroll
    for (int e = 0; e < NEXP; ++e) { p[e] = __expf(lg[e] - m); sum += p[e]; }
    const float isum = 1.0f / sum;
#pragma unroll
    for (int e = 0; e < NEXP; ++e) p[e] *= isum;
    bool used[NEXP] = {};
    for (int k = 0; k < TOPKE; ++k) {
      int best = -1; float bv = -1.f;
      for (int e = 0; e < NEXP; ++e)
        if (!used[e] && p[e] > bv) { bv = p[e]; best = e; }
      used[best] = true;
      eidx[t * TOPKE + k] = best;
      gates[t * TOPKE + k] = bv;
      atomicAdd(&counts[best], 1);
    }
  }
}

__global__ void k_zero(int* p) { if (threadIdx.x < 16) p[threadIdx.x] = 0; }

__global__ void k_prefix(const int* __restrict__ counts, int* __restrict__ offs,
                         int* __restrict__ cursor, int* __restrict__ tile_e,
                         int* __restrict__ tile_r0, int* __restrict__ ntiles) {
  if (threadIdx.x == 0 && blockIdx.x == 0) {
    int off = 0, nt = 0;
    for (int e = 0; e < NEXP; ++e) {
      offs[e] = off; cursor[e] = off;
      const int c = counts[e];
      for (int r0 = 0; r0 < c; r0 += 128) { tile_e[nt] = e; tile_r0[nt] = r0; ++nt; }
      off += c;
    }
    *ntiles = nt;
  }
}

__global__ __launch_bounds__(256) void k_scatter(const int* __restrict__ eidx,
                                                 const float* __restrict__ gates,
                                                 int* __restrict__ cursor,
                                                 int* __restrict__ row_slot,
                                                 float* __restrict__ gate_slot,
                                                 int* __restrict__ slot_of) {
  const int i = blockIdx.x * blockDim.x + threadIdx.x;
  if (i >= NSLOT) return;
  const int e = eidx[i];
  const int pos = atomicAdd(&cursor[e], 1);
  row_slot[pos] = i / TOPKE;
  gate_slot[pos] = gates[i];
  slot_of[i] = pos;
}

// ---------------- combine: h += shared + sum_k routed_down[slot] ----------------
__global__ __launch_bounds__(256) void k_combine(float* __restrict__ h,
                                                 const float* __restrict__ sh,
                                                 const float* __restrict__ rd,
                                                 const int* __restrict__ slot_of) {
  const int t = blockIdx.x;
  const int s0 = slot_of[t * 3 + 0], s1 = slot_of[t * 3 + 1], s2 = slot_of[t * 3 + 2];
  const float4* shp = (const float4*)(sh + (size_t)t * HD);
  const float4* r0 = (const float4*)(rd + (size_t)s0 * HD);
  const float4* r1 = (const float4*)(rd + (size_t)s1 * HD);
  const float4* r2 = (const float4*)(rd + (size_t)s2 * HD);
  float4* hp = (float4*)(h + (size_t)t * HD);
  const int i = threadIdx.x;
  float4 hv = hp[i], a = shp[i], b0 = r0[i], b1 = r1[i], b2 = r2[i];
  hv.x += a.x + b0.x + b1.x + b2.x;
  hv.y += a.y + b0.y + b1.y + b2.y;
  hv.z += a.z + b0.z + b1.z + b2.z;
  hv.w += a.w + b0.w + b1.w + b2.w;
  hp[i] = hv;
}

// ---------------- tied head: logits[b][v] = dot(hf[b], Wemb[v]) ----------------
__global__ __launch_bounds__(256) void k_head(const float* __restrict__ hf,
                                              const float* __restrict__ Wemb,
                                              float* __restrict__ out) {
  __shared__ float hs[4][HD];
  const int tid = threadIdx.x;
  for (int i = tid; i < HD; i += 256) {
    hs[0][i] = hf[i]; hs[1][i] = hf[HD + i];
    hs[2][i] = hf[2 * HD + i]; hs[3][i] = hf[3 * HD + i];
  }
  __syncthreads();
  const int w = tid >> 6, lane = tid & 63;
  for (int i = 0; i < 4; ++i) {
    const int v = blockIdx.x * 16 + w * 4 + i;
    const float4* wr = (const float4*)(Wemb + (size_t)v * HD);
    float a0 = 0.f, a1 = 0.f, a2 = 0.f, a3 = 0.f;
    for (int q = lane; q < HD / 4; q += 64) {
      float4 wv = wr[q];
      const int k = q * 4;
      a0 += wv.x * hs[0][k] + wv.y * hs[0][k + 1] + wv.z * hs[0][k + 2] + wv.w * hs[0][k + 3];
      a1 += wv.x * hs[1][k] + wv.y * hs[1][k + 1] + wv.z * hs[1][k + 2] + wv.w * hs[1][k + 3];
      a2 += wv.x * hs[2][k] + wv.y * hs[2][k + 1] + wv.z * hs[2][k + 2] + wv.w * hs[2][k + 3];
      a3 += wv.x * hs[3][k] + wv.y * hs[3][k + 1] + wv.z * hs[3][k + 2] + wv.w * hs[3][k + 3];
    }
#pragma unroll
    for (int o = 32; o > 0; o >>= 1) {
      a0 += __shfl_down(a0, o); a1 += __shfl_down(a1, o);
      a2 += __shfl_down(a2, o); a3 += __shfl_down(a3, o);
    }
    if (lane == 0) {
      out[v] = a0; out[NVOCAB + v] = a1;
      out[2 * NVOCAB + v] = a2; out[3 * NVOCAB + v] = a3;
    }
  }
}

extern "C" void kernel_launch(void* const* d_in, const int* in_sizes, int n_in,
                              void* d_out, int out_size, void* d_ws, size_t ws_size,
                              hipStream_t stream) {
  (void)in_sizes; (void)n_in; (void)out_size; (void)ws_size;
  const int* x = (const int*)d_in[0];
  const float* W_emb = (const float*)d_in[1];
  const float* W_pos = (const float*)d_in[2];
  const float* ln1_g = (const float*)d_in[3];
  const float* ln1_b = (const float*)d_in[4];
  const float* Wqkv = (const float*)d_in[5];
  const float* Wo = (const float*)d_in[6];
  const float* ln2_g = (const float*)d_in[7];
  const float* ln2_b = (const float*)d_in[8];
  const float* Wr = (const float*)d_in[9];
  const float* Wsu = (const float*)d_in[10];
  const float* Wsd = (const float*)d_in[11];
  const float* Wu = (const float*)d_in[12];
  const float* Wd = (const float*)d_in[13];
  const float* lnf_g = (const float*)d_in[14];
  const float* lnf_b = (const float*)d_in[15];
  float* out = (float*)d_out;

  float* wsf = (float*)d_ws;
  size_t o = 0;
  float* hbuf = wsf + o; o += (size_t)BT * HD;
  float* lno  = wsf + o; o += (size_t)BT * HD;
  float* qkvb = wsf + o; o += (size_t)BT * 3 * HD;    // bf16 qkv + vt; later routed_down
  float* ab   = wsf + o; o += (size_t)BT * HD;
  float* moe_out = wsf + o; o += (size_t)BT * HD;
  float* hf = wsf + o; o += 4 * HD;
  float* gates = wsf + o; o += NSLOT;
  float* gate_slot = wsf + o; o += NSLOT;
  int* eidx = (int*)(wsf + o); o += NSLOT;
  int* row_slot = (int*)(wsf + o); o += NSLOT;
  int* slot_of = (int*)(wsf + o); o += NSLOT;
  int* counts = (int*)(wsf + o); o += 16;
  int* offs = (int*)(wsf + o); o += 16;
  int* cursor = (int*)(wsf + o); o += 16;
  int* tile_e = (int*)(wsf + o); o += 256;
  int* tile_r0 = (int*)(wsf + o); o += 256;
  int* ntiles = (int*)(wsf + o); o += 16;
  // bf16 regions (2 bf16 per float slot)
  __hip_bfloat16* lno_bf = (__hip_bfloat16*)(wsf + o); o += (size_t)BT * HD / 2;
  __hip_bfloat16* ybf    = (__hip_bfloat16*)(wsf + o); o += (size_t)BT * HD / 2;
  __hip_bfloat16* shm_bf = (__hip_bfloat16*)(wsf + o); o += (size_t)BT * ED / 2;
  __hip_bfloat16* rup_bf = (__hip_bfloat16*)(wsf + o); o += (size_t)NSLOT * ED / 2;
  __hip_bfloat16* wqkv_t = (__hip_bfloat16*)(wsf + o); o += (size_t)NLAYER * HD * 3 * HD / 2;
  __hip_bfloat16* wo_t   = (__hip_bfloat16*)(wsf + o); o += (size_t)NLAYER * HD * HD / 2;
  __hip_bfloat16* wsu_t  = (__hip_bfloat16*)(wsf + o); o += (size_t)NLAYER * HD * ED / 2;
  __hip_bfloat16* wsd_t  = (__hip_bfloat16*)(wsf + o); o += (size_t)NLAYER * ED * HD / 2;
  __hip_bfloat16* wu_t   = (__hip_bfloat16*)(wsf + o); o += (size_t)NLAYER * NEXP * HD * ED / 2;
  __hip_bfloat16* wd_t   = (__hip_bfloat16*)(wsf + o); o += (size_t)NLAYER * NEXP * ED * HD / 2;
  float* routed_down = qkvb;                          // reused after attn
  __hip_bfloat16* qkv_bf = (__hip_bfloat16*)qkvb;     // BT*3HD bf16 (first half of region)
  __hip_bfloat16* vtb = qkv_bf + (size_t)BT * 3 * HD; // BT*HD bf16 (fits in region)

  // weight transpose+convert: [z][K][N] fp32 -> [z][N][K] bf16
  dim3 tb(32, 8);
  k_wtrans<<<dim3(3 * HD / 32, HD / 32, NLAYER), tb, 0, stream>>>(Wqkv, wqkv_t, HD, 3 * HD);
  k_wtrans<<<dim3(HD / 32, HD / 32, NLAYER), tb, 0, stream>>>(Wo, wo_t, HD, HD);
  k_wtrans<<<dim3(ED / 32, HD / 32, NLAYER), tb, 0, stream>>>(Wsu, wsu_t, HD, ED);
  k_wtrans<<<dim3(HD / 32, ED / 32, NLAYER), tb, 0, stream>>>(Wsd, wsd_t, ED, HD);
  k_wtrans<<<dim3(ED / 32, HD / 32, NLAYER * NEXP), tb, 0, stream>>>(Wu, wu_t, HD, ED);
  k_wtrans<<<dim3(HD / 32, ED / 32, NLAYER * NEXP), tb, 0, stream>>>(Wd, wd_t, ED, HD);

  k_embed<<<BT, 256, 0, stream>>>(x, W_emb, W_pos, hbuf);

  for (int l = 0; l < NLAYER; ++l) {
    k_ln<<<BT, 256, 0, stream>>>(hbuf, ln1_g + (size_t)l * HD, ln1_b + (size_t)l * HD,
                                 lno, lno_bf);
    k_mgemm<0, 1><<<dim3(24, 32), 256, 0, stream>>>(
        lno_bf, wqkv_t + (size_t)l * HD * 3 * HD, nullptr, nullptr, qkv_bf, BT, 3 * HD, HD);
    k_vtrans<<<dim3(64, 16), 256, 0, stream>>>(qkv_bf, vtb);
    k_mattn<<<dim3(64, 8), 256, 0, stream>>>(qkv_bf, vtb, ybf);
    k_mgemm<2, 0><<<dim3(8, 32), 256, 0, stream>>>(
        ybf, wo_t + (size_t)l * HD * HD, hbuf, ab, nullptr, BT, HD, HD);
    k_ln<<<BT, 256, 0, stream>>>(ab, ln2_g + (size_t)l * HD, ln2_b + (size_t)l * HD,
                                 lno, lno_bf);
    k_zero<<<1, 64, 0, stream>>>(counts);
    k_router<<<BT, 64, 0, stream>>>(lno, Wr + (size_t)l * HD * NEXP, gates, eidx, counts);
    k_prefix<<<1, 1, 0, stream>>>(counts, offs, cursor, tile_e, tile_r0, ntiles);
    k_scatter<<<(NSLOT + 255) / 256, 256, 0, stream>>>(eidx, gates, cursor, row_slot,
                                                       gate_slot, slot_of);
    // shared expert
    k_mgemm<1, 1><<<dim3(4, 32), 256, 0, stream>>>(
        lno_bf, wsu_t + (size_t)l * HD * ED, nullptr, nullptr, shm_bf, BT, ED, HD);
    k_mgemm<0, 0><<<dim3(8, 32), 256, 0, stream>>>(
        shm_bf, wsd_t + (size_t)l * ED * HD, nullptr, moe_out, nullptr, BT, HD, ED);
    // routed experts (top-3 only)
    k_mgemm_moe<1><<<dim3(4, 112), 256, 0, stream>>>(
        lno_bf, wu_t + (size_t)l * NEXP * HD * ED, nullptr, rup_bf,
        tile_e, tile_r0, ntiles, counts, offs, row_slot, gate_slot, ED, HD, 1);
    k_mgemm_moe<3><<<dim3(8, 112), 256, 0, stream>>>(
        rup_bf, wd_t + (size_t)l * NEXP * ED * HD, routed_down, nullptr,
        tile_e, tile_r0, ntiles, counts, offs, row_slot, gate_slot, HD, ED, 0);
    k_combine<<<BT, 256, 0, stream>>>(hbuf, moe_out, routed_down, slot_of);
  }

  k_lnf<<<4, 256, 0, stream>>>(hbuf, lnf_g, lnf_b, hf);
  k_head<<<NVOCAB / 16, 256, 0, stream>>>(hf, W_emb, out);
}

// Round 4
// 1602.823 us; speedup vs baseline: 4.1780x; 1.4559x over previous
//
#include <hip/hip_runtime.h>
#include <hip/hip_bf16.h>
#include <math.h>

#define BT 4096      // B*T tokens
#define HD 1024      // hidden
#define NHEAD 16
#define DH 64
#define ED 512       // expert dim
#define NEXP 10
#define TOPKE 3
#define NLAYER 4
#define NVOCAB 32000
#define NSLOT (BT * TOPKE)   // 12288

typedef __attribute__((ext_vector_type(8))) short bf16x8;
typedef __attribute__((ext_vector_type(4))) short bf16x4;
typedef __attribute__((ext_vector_type(4))) float f32x4;

__device__ __forceinline__ float gelu_f(float x) {
  return 0.5f * x * (1.0f + erff(x * 0.70710678118654752440f));
}

// async global->LDS, 16B per lane, 64 lanes = 1KB per call.
__device__ __forceinline__ void gll16(const void* g, void* l) {
  __builtin_amdgcn_global_load_lds(
      (const __attribute__((address_space(1))) unsigned int*)g,
      (__attribute__((address_space(3))) unsigned int*)l, 16, 0, 0);
}

// ---------------- embedding: h = W_emb[x] + W_pos[pos] ----------------
__global__ __launch_bounds__(256) void k_embed(const int* __restrict__ x,
                                               const float* __restrict__ Wemb,
                                               const float* __restrict__ Wpos,
                                               float* __restrict__ h) {
  const int t = blockIdx.x;
  const int pos = t & 1023;
  const int tok = x[t];
  const float4* we = (const float4*)(Wemb + (size_t)tok * HD);
  const float4* wp = (const float4*)(Wpos + (size_t)pos * HD);
  float4* ho = (float4*)(h + (size_t)t * HD);
  const int i = threadIdx.x;
  float4 a = we[i], b = wp[i];
  ho[i] = make_float4(a.x + b.x, a.y + b.y, a.z + b.z, a.w + b.w);
}

// ---------------- weight transpose + fp32->bf16: in [z][K][N] -> out [z][N][K]
__global__ __launch_bounds__(256) void k_wtrans(const float* __restrict__ in,
                                                __hip_bfloat16* __restrict__ out,
                                                int K, int N) {
  const int z = blockIdx.z;
  const float* src = in + (size_t)z * K * N;
  __hip_bfloat16* dst = out + (size_t)z * N * K;
  __shared__ float t[32][33];
  const int tx = threadIdx.x, ty = threadIdx.y;    // (32, 8)
  const int k0 = blockIdx.y * 32, n0 = blockIdx.x * 32;
  for (int r = ty; r < 32; r += 8) t[r][tx] = src[(size_t)(k0 + r) * N + n0 + tx];
  __syncthreads();
  for (int r = ty; r < 32; r += 8)
    dst[(size_t)(n0 + r) * K + k0 + tx] = __float2bfloat16(t[tx][r]);
}

// ---------------- router weight transpose: Wr [L][HD][NEXP] -> [L][NEXP][HD] --
__global__ __launch_bounds__(256) void k_wrtrans(const float* __restrict__ in,
                                                 float* __restrict__ out) {
  const int l = blockIdx.x;
  const float* src = in + (size_t)l * HD * NEXP;
  float* dst = out + (size_t)l * NEXP * HD;
  for (int idx = threadIdx.x; idx < NEXP * HD; idx += 256) {
    const int e = idx / HD, k = idx - e * HD;
    dst[idx] = src[(size_t)k * NEXP + e];
  }
}

// ---------------- V transpose per (b,h): qkv V part -> vt[(bh*64+d)][1024 t] --
__global__ __launch_bounds__(256) void k_vtrans(const __hip_bfloat16* __restrict__ qkv,
                                                __hip_bfloat16* __restrict__ vt) {
  const int bh = blockIdx.x, tt = blockIdx.y;
  const int b = bh >> 4, h = bh & 15;
  __shared__ __hip_bfloat16 t[64][72];
  for (int c = threadIdx.x; c < 512; c += 256) {
    int r = c >> 3, d0 = (c & 7) * 8;
    *(bf16x8*)&t[r][d0] =
        *(const bf16x8*)(qkv + ((size_t)(b * 1024 + tt * 64 + r)) * 3072 + 2048 + h * 64 + d0);
  }
  __syncthreads();
  for (int c = threadIdx.x; c < 512; c += 256) {
    int d = c >> 3, t0 = (c & 7) * 8;
    union { bf16x8 v; __hip_bfloat16 e[8]; } u;
#pragma unroll
    for (int j = 0; j < 8; ++j) u.e[j] = t[t0 + j][d];
    *(bf16x8*)(vt + ((size_t)(bh * 64 + d)) * 1024 + tt * 64 + t0) = u.v;
  }
}

// ---------------- layernorm over rows of HD (float4 single-pass) --------------
// outf may be nullptr (skip fp32 output)
__global__ __launch_bounds__(256) void k_ln(const float* __restrict__ in,
                                            const float* __restrict__ g,
                                            const float* __restrict__ b,
                                            float* __restrict__ outf,
                                            __hip_bfloat16* __restrict__ outb) {
  const int row = blockIdx.x;
  const int tid = threadIdx.x;
  const float4 v = ((const float4*)(in + (size_t)row * HD))[tid];
  float s = v.x + v.y + v.z + v.w;
  float ss = v.x * v.x + v.y * v.y + v.z * v.z + v.w * v.w;
#pragma unroll
  for (int o = 32; o > 0; o >>= 1) { s += __shfl_down(s, o); ss += __shfl_down(ss, o); }
  __shared__ float rs[4], rss[4];
  if ((tid & 63) == 0) { rs[tid >> 6] = s; rss[tid >> 6] = ss; }
  __syncthreads();
  const float S = rs[0] + rs[1] + rs[2] + rs[3];
  const float SS = rss[0] + rss[1] + rss[2] + rss[3];
  const float mean = S * (1.0f / HD);
  const float var = SS * (1.0f / HD) - mean * mean;
  const float inv = rsqrtf(var + 1e-5f);
  const float4 gg = ((const float4*)g)[tid];
  const float4 bb = ((const float4*)b)[tid];
  float o0 = (v.x - mean) * inv * gg.x + bb.x;
  float o1 = (v.y - mean) * inv * gg.y + bb.y;
  float o2 = (v.z - mean) * inv * gg.z + bb.z;
  float o3 = (v.w - mean) * inv * gg.w + bb.w;
  if (outf) ((float4*)(outf + (size_t)row * HD))[tid] = make_float4(o0, o1, o2, o3);
  union { bf16x4 v; __hip_bfloat16 e[4]; } u;
  u.e[0] = __float2bfloat16(o0); u.e[1] = __float2bfloat16(o1);
  u.e[2] = __float2bfloat16(o2); u.e[3] = __float2bfloat16(o3);
  *(bf16x4*)(outb + (size_t)row * HD + tid * 4) = u.v;
}

// final LN over the 4 last-token rows only
__global__ __launch_bounds__(256) void k_lnf(const float* __restrict__ h,
                                             const float* __restrict__ g,
                                             const float* __restrict__ b,
                                             float* __restrict__ hf) {
  const int row = blockIdx.x * 1024 + 1023;
  const int tid = threadIdx.x;
  const float* xr = h + (size_t)row * HD;
  float s = 0.f, ss = 0.f;
  for (int i = tid; i < HD; i += 256) { float v = xr[i]; s += v; ss += v * v; }
#pragma unroll
  for (int o = 32; o > 0; o >>= 1) { s += __shfl_down(s, o); ss += __shfl_down(ss, o); }
  __shared__ float rs[4], rss[4];
  if ((tid & 63) == 0) { rs[tid >> 6] = s; rss[tid >> 6] = ss; }
  __syncthreads();
  const float S = rs[0] + rs[1] + rs[2] + rs[3];
  const float SS = rss[0] + rss[1] + rss[2] + rss[3];
  const float mean = S * (1.0f / HD);
  const float var = SS * (1.0f / HD) - mean * mean;
  const float inv = rsqrtf(var + 1e-5f);
  float* orow = hf + (size_t)blockIdx.x * HD;
  for (int i = tid; i < HD; i += 256) {
    float v = xr[i];
    orow[i] = (v - mean) * inv * g[i] + b[i];
  }
}

// ---------------- bf16 MFMA GEMM: C[M,N] = A[M,K] @ Bt[N,K]^T ----------------
template <int EPI, int OBF>
__global__ __launch_bounds__(256) void k_mgemm(const __hip_bfloat16* __restrict__ A,
                                               const __hip_bfloat16* __restrict__ Bt,
                                               const float* __restrict__ R,
                                               float* __restrict__ C,
                                               __hip_bfloat16* __restrict__ Cb,
                                               int M, int N, int K) {
  __shared__ __hip_bfloat16 As[128 * 32];
  __shared__ __hip_bfloat16 Bs[128 * 32];
  const int tid = threadIdx.x;
  const int w = tid >> 6, lane = tid & 63;
  const int wr = w >> 1, wc = w & 1;
  const int m0 = blockIdx.y << 7, n0 = blockIdx.x << 7;
  const int srow = lane >> 2;
  const int scol = (lane & 3) * 8;
  const int kq = (lane >> 4) * 8;
  int aidx[4], bidx[4];
#pragma unroll
  for (int m = 0; m < 4; ++m) aidx[m] = (wr * 64 + m * 16 + (lane & 15)) * 32 + kq;
#pragma unroll
  for (int n = 0; n < 4; ++n) bidx[n] = (wc * 64 + n * 16 + (lane & 15)) * 32 + kq;

  f32x4 acc[4][4];
#pragma unroll
  for (int m = 0; m < 4; ++m)
#pragma unroll
    for (int n = 0; n < 4; ++n) acc[m][n] = (f32x4){0.f, 0.f, 0.f, 0.f};

  const __hip_bfloat16* ga = A + (size_t)(m0 + w * 32 + srow) * K + scol;
  const __hip_bfloat16* gb = Bt + (size_t)(n0 + w * 32 + srow) * K + scol;
  __hip_bfloat16* la0 = &As[(w * 32) * 32];
  __hip_bfloat16* la1 = &As[(w * 32 + 16) * 32];
  __hip_bfloat16* lb0 = &Bs[(w * 32) * 32];
  __hip_bfloat16* lb1 = &Bs[(w * 32 + 16) * 32];

  for (int k0 = 0; k0 < K; k0 += 32) {
    gll16(ga + k0, la0);
    gll16(ga + (size_t)16 * K + k0, la1);
    gll16(gb + k0, lb0);
    gll16(gb + (size_t)16 * K + k0, lb1);
    __syncthreads();
    bf16x8 af[4], bfv[4];
#pragma unroll
    for (int m = 0; m < 4; ++m) af[m] = *(const bf16x8*)&As[aidx[m]];
#pragma unroll
    for (int n = 0; n < 4; ++n) bfv[n] = *(const bf16x8*)&Bs[bidx[n]];
#pragma unroll
    for (int m = 0; m < 4; ++m)
#pragma unroll
      for (int n = 0; n < 4; ++n)
        acc[m][n] = __builtin_amdgcn_mfma_f32_16x16x32_bf16(af[m], bfv[n], acc[m][n], 0, 0, 0);
    __syncthreads();
  }

#pragma unroll
  for (int m = 0; m < 4; ++m) {
#pragma unroll
    for (int n = 0; n < 4; ++n) {
#pragma unroll
      for (int r = 0; r < 4; ++r) {
        const int row = m0 + wr * 64 + m * 16 + (lane >> 4) * 4 + r;
        const int col = n0 + wc * 64 + n * 16 + (lane & 15);
        float v = acc[m][n][r];
        if (EPI == 1) v = gelu_f(v);
        if (EPI == 2) v += R[(size_t)row * N + col];
        if (OBF) Cb[(size_t)row * N + col] = __float2bfloat16(v);
        else C[(size_t)row * N + col] = v;
      }
    }
  }
}

// ---------------- grouped MoE bf16 MFMA GEMM over expert-sorted slots ----------
template <int EPI>
__global__ __launch_bounds__(256) void k_mgemm_moe(const __hip_bfloat16* __restrict__ A,
                                                   const __hip_bfloat16* __restrict__ Btbase,
                                                   float* __restrict__ C,
                                                   __hip_bfloat16* __restrict__ Cb,
                                                   const int* __restrict__ tile_e,
                                                   const int* __restrict__ tile_r0,
                                                   const int* __restrict__ ntiles,
                                                   const int* __restrict__ counts,
                                                   const int* __restrict__ offs,
                                                   const int* __restrict__ row_slot,
                                                   const float* __restrict__ gate_slot,
                                                   int N, int K, int gather) {
  const int tile = blockIdx.y;
  if (tile >= *ntiles) return;
  const int e = tile_e[tile], r0 = tile_r0[tile];
  const int cnt = counts[e], off = offs[e];
  const __hip_bfloat16* Bt = Btbase + (size_t)e * N * K;

  __shared__ __hip_bfloat16 As[128 * 32];
  __shared__ __hip_bfloat16 Bs[128 * 32];
  const int tid = threadIdx.x;
  const int w = tid >> 6, lane = tid & 63;
  const int wr = w >> 1, wc = w & 1;
  const int n0 = blockIdx.x << 7;
  const int srow = lane >> 2;
  const int scol = (lane & 3) * 8;
  const int kq = (lane >> 4) * 8;
  int aidx[4], bidx[4];
#pragma unroll
  for (int m = 0; m < 4; ++m) aidx[m] = (wr * 64 + m * 16 + (lane & 15)) * 32 + kq;
#pragma unroll
  for (int n = 0; n < 4; ++n) bidx[n] = (wc * 64 + n * 16 + (lane & 15)) * 32 + kq;

  const int last = off + cnt - 1;
  int s0 = off + r0 + w * 32 + srow;        if (s0 > last) s0 = last;
  int s1 = off + r0 + w * 32 + 16 + srow;   if (s1 > last) s1 = last;
  const int arow0 = gather ? row_slot[s0] : s0;
  const int arow1 = gather ? row_slot[s1] : s1;

  f32x4 acc[4][4];
#pragma unroll
  for (int m = 0; m < 4; ++m)
#pragma unroll
    for (int n = 0; n < 4; ++n) acc[m][n] = (f32x4){0.f, 0.f, 0.f, 0.f};

  const __hip_bfloat16* ga0 = A + (size_t)arow0 * K + scol;
  const __hip_bfloat16* ga1 = A + (size_t)arow1 * K + scol;
  const __hip_bfloat16* gb = Bt + (size_t)(n0 + w * 32 + srow) * K + scol;
  __hip_bfloat16* la0 = &As[(w * 32) * 32];
  __hip_bfloat16* la1 = &As[(w * 32 + 16) * 32];
  __hip_bfloat16* lb0 = &Bs[(w * 32) * 32];
  __hip_bfloat16* lb1 = &Bs[(w * 32 + 16) * 32];

  for (int k0 = 0; k0 < K; k0 += 32) {
    gll16(ga0 + k0, la0);
    gll16(ga1 + k0, la1);
    gll16(gb + k0, lb0);
    gll16(gb + (size_t)16 * K + k0, lb1);
    __syncthreads();
    bf16x8 af[4], bfv[4];
#pragma unroll
    for (int m = 0; m < 4; ++m) af[m] = *(const bf16x8*)&As[aidx[m]];
#pragma unroll
    for (int n = 0; n < 4; ++n) bfv[n] = *(const bf16x8*)&Bs[bidx[n]];
#pragma unroll
    for (int m = 0; m < 4; ++m)
#pragma unroll
      for (int n = 0; n < 4; ++n)
        acc[m][n] = __builtin_amdgcn_mfma_f32_16x16x32_bf16(af[m], bfv[n], acc[m][n], 0, 0, 0);
    __syncthreads();
  }

#pragma unroll
  for (int m = 0; m < 4; ++m) {
#pragma unroll
    for (int r = 0; r < 4; ++r) {
      const int rl = wr * 64 + m * 16 + (lane >> 4) * 4 + r;
      if (r0 + rl < cnt) {
        const int slot = off + r0 + rl;
        const float sc = (EPI == 3) ? gate_slot[slot] : 1.0f;
#pragma unroll
        for (int n = 0; n < 4; ++n) {
          const int col = n0 + wc * 64 + n * 16 + (lane & 15);
          float v = acc[m][n][r];
          if (EPI == 1) {
            Cb[(size_t)slot * N + col] = __float2bfloat16(gelu_f(v));
          } else {
            C[(size_t)slot * N + col] = v * sc;
          }
        }
      }
    }
  }
}

// ---------------- MFMA flash attention (swapped QK^T), 128 q rows / block -----
__global__ __launch_bounds__(256) void k_mattn(const __hip_bfloat16* __restrict__ qkv,
                                               const __hip_bfloat16* __restrict__ vt,
                                               __hip_bfloat16* __restrict__ y) {
  const int bh = blockIdx.x;
  const int qt = 7 - (int)blockIdx.y;          // big causal blocks first
  const int b = bh >> 4, hh = bh & 15;
  const int tid = threadIdx.x;
  const int w = tid >> 6, lane = tid & 63;
  const int l15 = lane & 15, g = lane >> 4;
  const int swl = (l15 & 7) << 3;

  __shared__ __hip_bfloat16 Ks[64 * 64];
  __shared__ __hip_bfloat16 Vs[64 * 64];
  __shared__ __hip_bfloat16 Pw[2][4][16 * 64];

  bf16x8 qf[2][2];
#pragma unroll
  for (int s = 0; s < 2; ++s) {
    const __hip_bfloat16* qp =
        qkv + ((size_t)(b * 1024 + qt * 128 + s * 64 + w * 16 + l15)) * 3072 + hh * 64 + g * 8;
    qf[s][0] = *(const bf16x8*)qp;
    qf[s][1] = *(const bf16x8*)(qp + 32);
  }

  f32x4 yacc[2][4];
#pragma unroll
  for (int s = 0; s < 2; ++s)
#pragma unroll
    for (int nt = 0; nt < 4; ++nt) yacc[s][nt] = (f32x4){0.f, 0.f, 0.f, 0.f};
  float m_s[2] = {-INFINITY, -INFINITY};
  float l_s[2] = {0.f, 0.f};
  const int qg0 = qt * 128 + w * 16 + l15;

  const int ktmax = 2 * qt + 1;
  for (int kt = 0; kt <= ktmax; ++kt) {
    __syncthreads();
#pragma unroll
    for (int c0 = 0; c0 < 512; c0 += 256) {
      const int c = c0 + tid;
      const int r = c >> 3, cc = (c & 7) * 8;
      const int sw = cc ^ ((r & 7) << 3);
      *(bf16x8*)&Ks[r * 64 + sw] =
          *(const bf16x8*)(qkv + ((size_t)(b * 1024 + kt * 64 + r)) * 3072 + 1024 + hh * 64 + cc);
      *(bf16x8*)&Vs[r * 64 + sw] =
          *(const bf16x8*)(vt + ((size_t)(bh * 64 + r)) * 1024 + kt * 64 + cc);
    }
    __syncthreads();
    bf16x8 kf[4][2];
#pragma unroll
    for (int m = 0; m < 4; ++m) {
      const int row = m * 16 + l15;
#pragma unroll
      for (int kk = 0; kk < 2; ++kk)
        kf[m][kk] = *(const bf16x8*)&Ks[row * 64 + ((kk * 32 + g * 8) ^ swl)];
    }
    bf16x8 pa[2][2] = {};
#pragma unroll
    for (int s = 0; s < 2; ++s) {
      if (kt > 2 * qt + s) continue;
      f32x4 st[4];
#pragma unroll
      for (int m = 0; m < 4; ++m) st[m] = (f32x4){0.f, 0.f, 0.f, 0.f};
#pragma unroll
      for (int m = 0; m < 4; ++m)
#pragma unroll
        for (int kk = 0; kk < 2; ++kk)
          st[m] = __builtin_amdgcn_mfma_f32_16x16x32_bf16(kf[m][kk], qf[s][kk], st[m], 0, 0, 0);
      const int qg = qg0 + s * 64;
      const bool dia = (kt == 2 * qt + s);
      float tmax = -INFINITY;
#pragma unroll
      for (int m = 0; m < 4; ++m)
#pragma unroll
        for (int r = 0; r < 4; ++r) {
          float v = st[m][r] * 0.125f;
          if (dia && (kt * 64 + m * 16 + g * 4 + r) > qg) v = -INFINITY;
          st[m][r] = v;
          tmax = fmaxf(tmax, v);
        }
      tmax = fmaxf(tmax, __shfl_xor(tmax, 16));
      tmax = fmaxf(tmax, __shfl_xor(tmax, 32));
      const float mnew = fmaxf(m_s[s], tmax);
      const float fac = __expf(m_s[s] - mnew);
      m_s[s] = mnew;
      float tsum = 0.f;
#pragma unroll
      for (int m = 0; m < 4; ++m)
#pragma unroll
        for (int r = 0; r < 4; ++r) {
          float p = __expf(st[m][r] - mnew);
          st[m][r] = p;
          tsum += p;
        }
      tsum += __shfl_xor(tsum, 16);
      tsum += __shfl_xor(tsum, 32);
      l_s[s] = l_s[s] * fac + tsum;
      float fq[4];
#pragma unroll
      for (int r = 0; r < 4; ++r) fq[r] = __shfl(fac, g * 4 + r);
#pragma unroll
      for (int nt = 0; nt < 4; ++nt)
#pragma unroll
        for (int r = 0; r < 4; ++r) yacc[s][nt][r] *= fq[r];
#pragma unroll
      for (int m = 0; m < 4; ++m) {
        union { bf16x4 v; __hip_bfloat16 e[4]; } pk;
#pragma unroll
        for (int r = 0; r < 4; ++r) pk.e[r] = __float2bfloat16(st[m][r]);
        *(bf16x4*)&Pw[s][w][l15 * 64 + ((m * 16 + g * 4) ^ swl)] = pk.v;
      }
#pragma unroll
      for (int kk = 0; kk < 2; ++kk)
        pa[s][kk] = *(const bf16x8*)&Pw[s][w][l15 * 64 + ((kk * 32 + g * 8) ^ swl)];
    }
    const bool v0 = (kt <= 2 * qt);
#pragma unroll
    for (int kk = 0; kk < 2; ++kk)
#pragma unroll
      for (int nt = 0; nt < 4; ++nt) {
        bf16x8 vf = *(const bf16x8*)&Vs[(nt * 16 + l15) * 64 + ((kk * 32 + g * 8) ^ swl)];
        if (v0) yacc[0][nt] = __builtin_amdgcn_mfma_f32_16x16x32_bf16(pa[0][kk], vf, yacc[0][nt], 0, 0, 0);
        yacc[1][nt] = __builtin_amdgcn_mfma_f32_16x16x32_bf16(pa[1][kk], vf, yacc[1][nt], 0, 0, 0);
      }
  }
#pragma unroll
  for (int s = 0; s < 2; ++s) {
    const float inv = 1.0f / l_s[s];
    float iq[4];
#pragma unroll
    for (int r = 0; r < 4; ++r) iq[r] = __shfl(inv, g * 4 + r);
#pragma unroll
    for (int r = 0; r < 4; ++r) {
      __hip_bfloat16* yp =
          y + ((size_t)(b * 1024 + qt * 128 + s * 64 + w * 16 + g * 4 + r)) * HD + hh * 64 + l15;
#pragma unroll
      for (int nt = 0; nt < 4; ++nt)
        yp[nt * 16] = __float2bfloat16(yacc[s][nt][r] * iq[r]);
    }
  }
}

// ---------------- router v2: one wave per token, no atomics ----------------
// Wrt: [NEXP][HD] fp32 (transposed). Writes eidx/gates only.
__global__ __launch_bounds__(256) void k_router2(const float* __restrict__ xln,
                                                 const float* __restrict__ Wrt,
                                                 float* __restrict__ gates,
                                                 int* __restrict__ eidx) {
  const int w = threadIdx.x >> 6, lane = threadIdx.x & 63;
  const int t = blockIdx.x * 4 + w;
  const float4* xr4 = (const float4*)(xln + (size_t)t * HD);
  float4 xv[4];
#pragma unroll
  for (int i = 0; i < 4; ++i) xv[i] = xr4[lane + i * 64];
  float partial[NEXP];
#pragma unroll
  for (int e = 0; e < NEXP; ++e) {
    const float4* wr4 = (const float4*)(Wrt + (size_t)e * HD);
    float a = 0.f;
#pragma unroll
    for (int i = 0; i < 4; ++i) {
      float4 wv = wr4[lane + i * 64];
      a += xv[i].x * wv.x + xv[i].y * wv.y + xv[i].z * wv.z + xv[i].w * wv.w;
    }
    partial[e] = a;
  }
#pragma unroll
  for (int e = 0; e < NEXP; ++e) {
    float v = partial[e];
#pragma unroll
    for (int o = 32; o > 0; o >>= 1) v += __shfl_down(v, o);
    partial[e] = v;
  }
  if (lane == 0) {
    float m = partial[0];
#pragma unroll
    for (int e = 1; e < NEXP; ++e) m = fmaxf(m, partial[e]);
    float p[NEXP], sum = 0.f;
#pragma unroll
    for (int e = 0; e < NEXP; ++e) { p[e] = __expf(partial[e] - m); sum += p[e]; }
    const float isum = 1.0f / sum;
#pragma unroll
    for (int e = 0; e < NEXP; ++e) p[e] *= isum;
    bool used[NEXP] = {};
    for (int k = 0; k < TOPKE; ++k) {
      int best = -1; float bv = -1.f;
      for (int e = 0; e < NEXP; ++e)
        if (!used[e] && p[e] > bv) { bv = p[e]; best = e; }
      used[best] = true;
      eidx[t * TOPKE + k] = best;
      gates[t * TOPKE + k] = bv;
    }
  }
}

// ---------------- MoE setup: counts + prefix + tiles + scatter, one block -----
__global__ __launch_bounds__(1024) void k_moe_setup(const int* __restrict__ eidx,
                                                    const float* __restrict__ gates,
                                                    int* __restrict__ counts,
                                                    int* __restrict__ offs,
                                                    int* __restrict__ tile_e,
                                                    int* __restrict__ tile_r0,
                                                    int* __restrict__ ntiles,
                                                    int* __restrict__ row_slot,
                                                    float* __restrict__ gate_slot,
                                                    int* __restrict__ slot_of) {
  __shared__ int lcnt[NEXP], lcur[NEXP];
  const int tid = threadIdx.x;
  if (tid < NEXP) lcnt[tid] = 0;
  __syncthreads();
  for (int i = tid; i < NSLOT; i += 1024) atomicAdd(&lcnt[eidx[i]], 1);
  __syncthreads();
  if (tid == 0) {
    int off = 0, nt = 0;
    for (int e = 0; e < NEXP; ++e) {
      lcur[e] = off;
      counts[e] = lcnt[e];
      offs[e] = off;
      for (int r0 = 0; r0 < lcnt[e]; r0 += 128) { tile_e[nt] = e; tile_r0[nt] = r0; ++nt; }
      off += lcnt[e];
    }
    *ntiles = nt;
  }
  __syncthreads();
  for (int i = tid; i < NSLOT; i += 1024) {
    const int e = eidx[i];
    const int pos = atomicAdd(&lcur[e], 1);
    row_slot[pos] = i / TOPKE;
    gate_slot[pos] = gates[i];
    slot_of[i] = pos;
  }
}

// ---------------- combine: h += shared + sum_k routed_down[slot] ----------------
__global__ __launch_bounds__(256) void k_combine(float* __restrict__ h,
                                                 const float* __restrict__ sh,
                                                 const float* __restrict__ rd,
                                                 const int* __restrict__ slot_of) {
  const int t = blockIdx.x;
  const int s0 = slot_of[t * 3 + 0], s1 = slot_of[t * 3 + 1], s2 = slot_of[t * 3 + 2];
  const float4* shp = (const float4*)(sh + (size_t)t * HD);
  const float4* r0 = (const float4*)(rd + (size_t)s0 * HD);
  const float4* r1 = (const float4*)(rd + (size_t)s1 * HD);
  const float4* r2 = (const float4*)(rd + (size_t)s2 * HD);
  float4* hp = (float4*)(h + (size_t)t * HD);
  const int i = threadIdx.x;
  float4 hv = hp[i], a = shp[i], b0 = r0[i], b1 = r1[i], b2 = r2[i];
  hv.x += a.x + b0.x + b1.x + b2.x;
  hv.y += a.y + b0.y + b1.y + b2.y;
  hv.z += a.z + b0.z + b1.z + b2.z;
  hv.w += a.w + b0.w + b1.w + b2.w;
  hp[i] = hv;
}

// ---------------- tied head: logits[b][v] = dot(hf[b], Wemb[v]) ----------------
__global__ __launch_bounds__(256) void k_head(const float* __restrict__ hf,
                                              const float* __restrict__ Wemb,
                                              float* __restrict__ out) {
  __shared__ float hs[4][HD];
  const int tid = threadIdx.x;
  for (int i = tid; i < HD; i += 256) {
    hs[0][i] = hf[i]; hs[1][i] = hf[HD + i];
    hs[2][i] = hf[2 * HD + i]; hs[3][i] = hf[3 * HD + i];
  }
  __syncthreads();
  const int w = tid >> 6, lane = tid & 63;
  for (int i = 0; i < 4; ++i) {
    const int v = blockIdx.x * 16 + w * 4 + i;
    const float4* wr = (const float4*)(Wemb + (size_t)v * HD);
    float a0 = 0.f, a1 = 0.f, a2 = 0.f, a3 = 0.f;
    for (int q = lane; q < HD / 4; q += 64) {
      float4 wv = wr[q];
      const int k = q * 4;
      a0 += wv.x * hs[0][k] + wv.y * hs[0][k + 1] + wv.z * hs[0][k + 2] + wv.w * hs[0][k + 3];
      a1 += wv.x * hs[1][k] + wv.y * hs[1][k + 1] + wv.z * hs[1][k + 2] + wv.w * hs[1][k + 3];
      a2 += wv.x * hs[2][k] + wv.y * hs[2][k + 1] + wv.z * hs[2][k + 2] + wv.w * hs[2][k + 3];
      a3 += wv.x * hs[3][k] + wv.y * hs[3][k + 1] + wv.z * hs[3][k + 2] + wv.w * hs[3][k + 3];
    }
#pragma unroll
    for (int o = 32; o > 0; o >>= 1) {
      a0 += __shfl_down(a0, o); a1 += __shfl_down(a1, o);
      a2 += __shfl_down(a2, o); a3 += __shfl_down(a3, o);
    }
    if (lane == 0) {
      out[v] = a0; out[NVOCAB + v] = a1;
      out[2 * NVOCAB + v] = a2; out[3 * NVOCAB + v] = a3;
    }
  }
}

extern "C" void kernel_launch(void* const* d_in, const int* in_sizes, int n_in,
                              void* d_out, int out_size, void* d_ws, size_t ws_size,
                              hipStream_t stream) {
  (void)in_sizes; (void)n_in; (void)out_size; (void)ws_size;
  const int* x = (const int*)d_in[0];
  const float* W_emb = (const float*)d_in[1];
  const float* W_pos = (const float*)d_in[2];
  const float* ln1_g = (const float*)d_in[3];
  const float* ln1_b = (const float*)d_in[4];
  const float* Wqkv = (const float*)d_in[5];
  const float* Wo = (const float*)d_in[6];
  const float* ln2_g = (const float*)d_in[7];
  const float* ln2_b = (const float*)d_in[8];
  const float* Wr = (const float*)d_in[9];
  const float* Wsu = (const float*)d_in[10];
  const float* Wsd = (const float*)d_in[11];
  const float* Wu = (const float*)d_in[12];
  const float* Wd = (const float*)d_in[13];
  const float* lnf_g = (const float*)d_in[14];
  const float* lnf_b = (const float*)d_in[15];
  float* out = (float*)d_out;

  float* wsf = (float*)d_ws;
  size_t o = 0;
  float* hbuf = wsf + o; o += (size_t)BT * HD;
  float* lno  = wsf + o; o += (size_t)BT * HD;
  float* qkvb = wsf + o; o += (size_t)BT * 3 * HD;    // bf16 qkv + vt; later routed_down
  float* ab   = wsf + o; o += (size_t)BT * HD;
  float* moe_out = wsf + o; o += (size_t)BT * HD;
  float* hf = wsf + o; o += 4 * HD;
  float* gates = wsf + o; o += NSLOT;
  float* gate_slot = wsf + o; o += NSLOT;
  int* eidx = (int*)(wsf + o); o += NSLOT;
  int* row_slot = (int*)(wsf + o); o += NSLOT;
  int* slot_of = (int*)(wsf + o); o += NSLOT;
  int* counts = (int*)(wsf + o); o += 16;
  int* offs = (int*)(wsf + o); o += 16;
  int* tile_e = (int*)(wsf + o); o += 256;
  int* tile_r0 = (int*)(wsf + o); o += 256;
  int* ntiles = (int*)(wsf + o); o += 16;
  float* wr_t = wsf + o; o += (size_t)NLAYER * NEXP * HD;
  // bf16 regions (2 bf16 per float slot)
  __hip_bfloat16* lno_bf = (__hip_bfloat16*)(wsf + o); o += (size_t)BT * HD / 2;
  __hip_bfloat16* ybf    = (__hip_bfloat16*)(wsf + o); o += (size_t)BT * HD / 2;
  __hip_bfloat16* shm_bf = (__hip_bfloat16*)(wsf + o); o += (size_t)BT * ED / 2;
  __hip_bfloat16* rup_bf = (__hip_bfloat16*)(wsf + o); o += (size_t)NSLOT * ED / 2;
  __hip_bfloat16* wqkv_t = (__hip_bfloat16*)(wsf + o); o += (size_t)NLAYER * HD * 3 * HD / 2;
  __hip_bfloat16* wo_t   = (__hip_bfloat16*)(wsf + o); o += (size_t)NLAYER * HD * HD / 2;
  __hip_bfloat16* wsu_t  = (__hip_bfloat16*)(wsf + o); o += (size_t)NLAYER * HD * ED / 2;
  __hip_bfloat16* wsd_t  = (__hip_bfloat16*)(wsf + o); o += (size_t)NLAYER * ED * HD / 2;
  __hip_bfloat16* wu_t   = (__hip_bfloat16*)(wsf + o); o += (size_t)NLAYER * NEXP * HD * ED / 2;
  __hip_bfloat16* wd_t   = (__hip_bfloat16*)(wsf + o); o += (size_t)NLAYER * NEXP * ED * HD / 2;
  float* routed_down = qkvb;                          // reused after attn
  __hip_bfloat16* qkv_bf = (__hip_bfloat16*)qkvb;     // BT*3HD bf16
  __hip_bfloat16* vtb = qkv_bf + (size_t)BT * 3 * HD; // BT*HD bf16

  // weight transpose+convert: [z][K][N] fp32 -> [z][N][K] bf16
  dim3 tb(32, 8);
  k_wtrans<<<dim3(3 * HD / 32, HD / 32, NLAYER), tb, 0, stream>>>(Wqkv, wqkv_t, HD, 3 * HD);
  k_wtrans<<<dim3(HD / 32, HD / 32, NLAYER), tb, 0, stream>>>(Wo, wo_t, HD, HD);
  k_wtrans<<<dim3(ED / 32, HD / 32, NLAYER), tb, 0, stream>>>(Wsu, wsu_t, HD, ED);
  k_wtrans<<<dim3(HD / 32, ED / 32, NLAYER), tb, 0, stream>>>(Wsd, wsd_t, ED, HD);
  k_wtrans<<<dim3(ED / 32, HD / 32, NLAYER * NEXP), tb, 0, stream>>>(Wu, wu_t, HD, ED);
  k_wtrans<<<dim3(HD / 32, ED / 32, NLAYER * NEXP), tb, 0, stream>>>(Wd, wd_t, ED, HD);
  k_wrtrans<<<NLAYER, 256, 0, stream>>>(Wr, wr_t);

  k_embed<<<BT, 256, 0, stream>>>(x, W_emb, W_pos, hbuf);

  for (int l = 0; l < NLAYER; ++l) {
    k_ln<<<BT, 256, 0, stream>>>(hbuf, ln1_g + (size_t)l * HD, ln1_b + (size_t)l * HD,
                                 nullptr, lno_bf);
    k_mgemm<0, 1><<<dim3(24, 32), 256, 0, stream>>>(
        lno_bf, wqkv_t + (size_t)l * HD * 3 * HD, nullptr, nullptr, qkv_bf, BT, 3 * HD, HD);
    k_vtrans<<<dim3(64, 16), 256, 0, stream>>>(qkv_bf, vtb);
    k_mattn<<<dim3(64, 8), 256, 0, stream>>>(qkv_bf, vtb, ybf);
    k_mgemm<2, 0><<<dim3(8, 32), 256, 0, stream>>>(
        ybf, wo_t + (size_t)l * HD * HD, hbuf, ab, nullptr, BT, HD, HD);
    k_ln<<<BT, 256, 0, stream>>>(ab, ln2_g + (size_t)l * HD, ln2_b + (size_t)l * HD,
                                 lno, lno_bf);
    k_router2<<<BT / 4, 256, 0, stream>>>(lno, wr_t + (size_t)l * NEXP * HD, gates, eidx);
    k_moe_setup<<<1, 1024, 0, stream>>>(eidx, gates, counts, offs, tile_e, tile_r0,
                                        ntiles, row_slot, gate_slot, slot_of);
    // shared expert
    k_mgemm<1, 1><<<dim3(4, 32), 256, 0, stream>>>(
        lno_bf, wsu_t + (size_t)l * HD * ED, nullptr, nullptr, shm_bf, BT, ED, HD);
    k_mgemm<0, 0><<<dim3(8, 32), 256, 0, stream>>>(
        shm_bf, wsd_t + (size_t)l * ED * HD, nullptr, moe_out, nullptr, BT, HD, ED);
    // routed experts (top-3 only)
    k_mgemm_moe<1><<<dim3(4, 112), 256, 0, stream>>>(
        lno_bf, wu_t + (size_t)l * NEXP * HD * ED, nullptr, rup_bf,
        tile_e, tile_r0, ntiles, counts, offs, row_slot, gate_slot, ED, HD, 1);
    k_mgemm_moe<3><<<dim3(8, 112), 256, 0, stream>>>(
        rup_bf, wd_t + (size_t)l * NEXP * ED * HD, routed_down, nullptr,
        tile_e, tile_r0, ntiles, counts, offs, row_slot, gate_slot, HD, ED, 0);
    k_combine<<<BT, 256, 0, stream>>>(hbuf, moe_out, routed_down, slot_of);
  }

  k_lnf<<<4, 256, 0, stream>>>(hbuf, lnf_g, lnf_b, hf);
  k_head<<<NVOCAB / 16, 256, 0, stream>>>(hf, W_emb, out);
}